// Round 6
// baseline (361.626 us; speedup 1.0000x reference)
//
#include <hip/hip_runtime.h>
#include <math.h>
#include <float.h>

#define B_    4
#define N_    2048
#define M_    8192
#define CIN_  512
#define COUT_ 256

// ---------------------------------------------------------------------------
// System-scope relaxed atomics for the d_ws producer->consumer handoff.
// These emit sc0/sc1 (bypass L1 + per-XCD L2, hit the coherence point), making
// inter-kernel visibility independent of graph-replay cache-op behavior.
// (Round-4 post-timing divergence: 0xAA poison lines stale in consumer-XCD L2.)
// ---------------------------------------------------------------------------
__device__ __forceinline__ void ws_store_f32(float* p, float v) {
    __hip_atomic_store((unsigned int*)p, __float_as_uint(v),
                       __ATOMIC_RELAXED, __HIP_MEMORY_SCOPE_SYSTEM);
}
__device__ __forceinline__ void ws_store_u32(int* p, int v) {
    __hip_atomic_store((unsigned int*)p, (unsigned int)v,
                       __ATOMIC_RELAXED, __HIP_MEMORY_SCOPE_SYSTEM);
}
__device__ __forceinline__ float ws_load_f32(const float* p) {
    return __uint_as_float(__hip_atomic_load((const unsigned int*)p,
                       __ATOMIC_RELAXED, __HIP_MEMORY_SCOPE_SYSTEM));
}
__device__ __forceinline__ int ws_load_u32(const int* p) {
    return (int)__hip_atomic_load((const unsigned int*)p,
                       __ATOMIC_RELAXED, __HIP_MEMORY_SCOPE_SYSTEM);
}

// ---------------------------------------------------------------------------
// Kernel A: f1t[b][n][c] = relu( bn( sum_ci w_up[c,ci]*x1[b,ci,n] ) )
// 64x64 output tile per block, 4x4 micro-tile per thread, K-chunks of 32.
// Epilogue transposes through LDS; f1t stores are system-scope (ws handoff).
// ---------------------------------------------------------------------------
__global__ __launch_bounds__(256) void up_conv_kernel(
    const float* __restrict__ x1, const float* __restrict__ w,
    const float* __restrict__ gam, const float* __restrict__ bet,
    const float* __restrict__ mu, const float* __restrict__ var,
    float* __restrict__ f1t)
{
    __shared__ float sm[4224];
    float* Ws = sm;          // [32][68]  Ws[k*68 + o]
    float* Xs = sm + 2176;   // [32][64]  Xs[k*64 + n]
    const int b = blockIdx.z;
    const int o0 = blockIdx.y * 64;
    const int n0 = blockIdx.x * 64;
    const int tid = threadIdx.x;
    const int tx = tid & 15, ty = tid >> 4;

    float acc[4][4] = {{0.f}};

    for (int kc = 0; kc < CIN_; kc += 32) {
        #pragma unroll
        for (int r = 0; r < 2; ++r) {
            int e = tid + r * 256;          // 512 float4 of W tile (64o x 32k)
            int o = e >> 3, k4 = e & 7;
            float4 v = *(const float4*)(w + (size_t)(o0 + o) * CIN_ + kc + k4 * 4);
            Ws[(k4*4+0)*68 + o] = v.x;
            Ws[(k4*4+1)*68 + o] = v.y;
            Ws[(k4*4+2)*68 + o] = v.z;
            Ws[(k4*4+3)*68 + o] = v.w;
        }
        #pragma unroll
        for (int r = 0; r < 2; ++r) {
            int e = tid + r * 256;          // 512 float4 of X tile (32k x 64n)
            int k = e >> 4, c4 = e & 15;
            *(float4*)(Xs + k*64 + c4*4) =
                *(const float4*)(x1 + ((size_t)(b * CIN_ + kc + k)) * N_ + n0 + c4*4);
        }
        __syncthreads();
        #pragma unroll
        for (int k = 0; k < 32; ++k) {
            float4 av = *(const float4*)(Ws + k*68 + ty*4);
            float4 bv = *(const float4*)(Xs + k*64 + tx*4);
            float a[4] = {av.x, av.y, av.z, av.w};
            float c[4] = {bv.x, bv.y, bv.z, bv.w};
            #pragma unroll
            for (int i = 0; i < 4; ++i)
                #pragma unroll
                for (int j = 0; j < 4; ++j)
                    acc[i][j] = fmaf(a[i], c[j], acc[i][j]);
        }
        __syncthreads();
    }

    // BN + ReLU, transpose via LDS, store f1t[b][n][c] (system-scope)
    float* S = sm; // [64][65]
    #pragma unroll
    for (int i = 0; i < 4; ++i) {
        int o = o0 + ty*4 + i;
        float sc = gam[o] / sqrtf(var[o] + 1e-5f);
        float sh = bet[o] - mu[o] * sc;
        #pragma unroll
        for (int j = 0; j < 4; ++j) {
            float v = fmaxf(acc[i][j] * sc + sh, 0.0f);
            S[(tx*4+j)*65 + ty*4+i] = v;
        }
    }
    __syncthreads();
    #pragma unroll
    for (int r = 0; r < 16; ++r) {
        int e = tid + r * 256;
        int n = e >> 6, o = e & 63;
        ws_store_f32(f1t + ((size_t)(b * N_) + n0 + n) * COUT_ + o0 + o, S[n*65 + o]);
    }
}

// ---------------------------------------------------------------------------
// Kernel B: three_nn + inverse-distance weights + p2 passthrough.
// 8 lanes per query over disjoint 256-candidate segments, butterfly-merged
// with lexicographic (d2, idx) tie-breaking -> identical top-3 set/order as a
// sequential stable scan. Per-candidate d^2 is BIT-IDENTICAL to the validated
// round-4/5 arithmetic:
//   s   = fma(z,z, fma(y,y, x*x))   (ascending FMA chain)
//   dot = fma(z,z', fma(y,y', x*x'))
//   d2  = max(fma(-2, dot, s2 + s1), 0)
// nn_idx/nn_w stores are system-scope (ws handoff).
// ---------------------------------------------------------------------------
__device__ __forceinline__ void lex_insert(float e, int j,
    float& D0, float& D1, float& D2, int& I0, int& I1, int& I2)
{
    bool l0 = (e < D0) || (e == D0 && j < I0);
    bool l1 = (e < D1) || (e == D1 && j < I1);
    bool l2 = (e < D2) || (e == D2 && j < I2);
    if (l2) {
        if (l0)      { D2=D1; I2=I1; D1=D0; I1=I0; D0=e; I0=j; }
        else if (l1) { D2=D1; I2=I1; D1=e;  I1=j; }
        else         { D2=e;  I2=j; }
    }
}

__global__ __launch_bounds__(256) void three_nn_kernel(
    const float* __restrict__ p1, const float* __restrict__ p2,
    int* __restrict__ nn_idx, float* __restrict__ nn_w,
    float* __restrict__ out1)
{
    __shared__ float p1x[N_], p1y[N_], p1z[N_], s1[N_];
    const int b = blockIdx.y;
    for (int n = threadIdx.x; n < N_; n += 256) {
        float x = p1[((size_t)(b*N_)+n)*3 + 0];
        float y = p1[((size_t)(b*N_)+n)*3 + 1];
        float z = p1[((size_t)(b*N_)+n)*3 + 2];
        p1x[n] = x; p1y[n] = y; p1z[n] = z;
        float t = x * x;
        t = fmaf(y, y, t);
        t = fmaf(z, z, t);
        s1[n] = t;
    }
    __syncthreads();

    const int m = blockIdx.x * 32 + (threadIdx.x >> 3);
    const int s = threadIdx.x & 7;
    const size_t pbase = ((size_t)(b*M_) + m) * 3;
    const float qx = p2[pbase+0], qy = p2[pbase+1], qz = p2[pbase+2];
    float s2 = qx * qx;
    s2 = fmaf(qy, qy, s2);
    s2 = fmaf(qz, qz, s2);

    float D0 = FLT_MAX, D1 = FLT_MAX, D2 = FLT_MAX;
    int   I0 = 0x7fffffff, I1 = 0x7fffffff, I2 = 0x7fffffff;
    const int base = s * 256;
    for (int t = 0; t < 256; ++t) {
        // stagger by s*4: banks (t+4s)%32 distinct across the 8 segments;
        // the 8 lanes sharing a bank have the same address -> broadcast.
        int n = base + ((t + s*4) & 255);
        float dot = qx * p1x[n];
        dot = fmaf(qy, p1y[n], dot);
        dot = fmaf(qz, p1z[n], dot);
        float d2 = fmaf(-2.0f, dot, s2 + s1[n]);
        d2 = fmaxf(d2, 0.0f);
        lex_insert(d2, n, D0, D1, D2, I0, I1, I2);
    }
    #pragma unroll
    for (int st = 1; st <= 4; st <<= 1) {
        float E0 = __shfl_xor(D0, st), E1 = __shfl_xor(D1, st), E2 = __shfl_xor(D2, st);
        int   J0 = __shfl_xor(I0, st), J1 = __shfl_xor(I1, st), J2 = __shfl_xor(I2, st);
        lex_insert(E0, J0, D0, D1, D2, I0, I1, I2);
        lex_insert(E1, J1, D0, D1, D2, I0, I1, I2);
        lex_insert(E2, J2, D0, D1, D2, I0, I1, I2);
    }
    if (s == 0) {
        float r0 = 1.0f / (D0 + 1e-8f);
        float r1 = 1.0f / (D1 + 1e-8f);
        float r2 = 1.0f / (D2 + 1e-8f);
        float sum = (r0 + r1) + r2;
        size_t o = ((size_t)(b*M_) + m) * 3;
        ws_store_u32(nn_idx + o+0, I0);
        ws_store_u32(nn_idx + o+1, I1);
        ws_store_u32(nn_idx + o+2, I2);
        ws_store_f32(nn_w + o+0, r0 / sum);
        ws_store_f32(nn_w + o+1, r1 / sum);
        ws_store_f32(nn_w + o+2, r2 / sum);
        out1[o+0] = qx; out1[o+1] = qy; out1[o+2] = qz;
    }
}

// ---------------------------------------------------------------------------
// Kernel C: out0[b][c][m] = relu(bn(sum_ci w_lat[c,ci]*x2[b,ci,m]))
//                           + sum_k nn_w[b,m,k] * f1t[b][idx[b,m,k]][c]
// GEMM from x2 (inputs, normal loads); f1t/nn_idx/nn_w via system-scope loads.
// ---------------------------------------------------------------------------
__global__ __launch_bounds__(256) void lat_interp_kernel(
    const float* __restrict__ x2, const float* __restrict__ w,
    const float* __restrict__ gam, const float* __restrict__ bet,
    const float* __restrict__ mu, const float* __restrict__ var,
    const float* __restrict__ f1t, const int* __restrict__ nn_idx,
    const float* __restrict__ nn_w, float* __restrict__ out0)
{
    __shared__ float sm[4224];
    float* Ws = sm;          // [32][68]
    float* Xs = sm + 2176;   // [32][64]
    const int b = blockIdx.z;
    const int o0 = blockIdx.y * 64;
    const int m0 = blockIdx.x * 64;
    const int tid = threadIdx.x;
    const int tx = tid & 15, ty = tid >> 4;

    float acc[4][4] = {{0.f}};

    for (int kc = 0; kc < COUT_; kc += 32) {
        #pragma unroll
        for (int r = 0; r < 2; ++r) {
            int e = tid + r * 256;
            int o = e >> 3, k4 = e & 7;
            float4 v = *(const float4*)(w + (size_t)(o0 + o) * COUT_ + kc + k4 * 4);
            Ws[(k4*4+0)*68 + o] = v.x;
            Ws[(k4*4+1)*68 + o] = v.y;
            Ws[(k4*4+2)*68 + o] = v.z;
            Ws[(k4*4+3)*68 + o] = v.w;
        }
        #pragma unroll
        for (int r = 0; r < 2; ++r) {
            int e = tid + r * 256;
            int k = e >> 4, c4 = e & 15;
            *(float4*)(Xs + k*64 + c4*4) =
                *(const float4*)(x2 + ((size_t)(b * COUT_ + kc + k)) * M_ + m0 + c4*4);
        }
        __syncthreads();
        #pragma unroll
        for (int k = 0; k < 32; ++k) {
            float4 av = *(const float4*)(Ws + k*68 + ty*4);
            float4 bv = *(const float4*)(Xs + k*64 + tx*4);
            float a[4] = {av.x, av.y, av.z, av.w};
            float c[4] = {bv.x, bv.y, bv.z, bv.w};
            #pragma unroll
            for (int i = 0; i < 4; ++i)
                #pragma unroll
                for (int j = 0; j < 4; ++j)
                    acc[i][j] = fmaf(a[i], c[j], acc[i][j]);
        }
        __syncthreads();
    }

    const int mb = m0 + tx * 4;
    int   idx[4][3];
    float wq[4][3];
    #pragma unroll
    for (int j = 0; j < 4; ++j)
        #pragma unroll
        for (int k = 0; k < 3; ++k) {
            size_t o = ((size_t)(b*M_) + mb + j) * 3 + k;
            idx[j][k] = ws_load_u32(nn_idx + o);
            wq[j][k]  = ws_load_f32(nn_w + o);
        }

    float val[4][4];
    #pragma unroll
    for (int i = 0; i < 4; ++i) {
        int c = o0 + ty*4 + i;
        float sc = gam[c] / sqrtf(var[c] + 1e-5f);
        float sh = bet[c] - mu[c] * sc;
        #pragma unroll
        for (int j = 0; j < 4; ++j)
            val[i][j] = fmaxf(acc[i][j] * sc + sh, 0.0f);
    }
    #pragma unroll
    for (int j = 0; j < 4; ++j)
        #pragma unroll
        for (int k = 0; k < 3; ++k) {
            const float* gp = f1t + ((size_t)(b*N_) + idx[j][k]) * COUT_ + o0 + ty*4;
            float wk = wq[j][k];
            val[0][j] = fmaf(wk, ws_load_f32(gp + 0), val[0][j]);
            val[1][j] = fmaf(wk, ws_load_f32(gp + 1), val[1][j]);
            val[2][j] = fmaf(wk, ws_load_f32(gp + 2), val[2][j]);
            val[3][j] = fmaf(wk, ws_load_f32(gp + 3), val[3][j]);
        }
    #pragma unroll
    for (int i = 0; i < 4; ++i) {
        float4 o4 = make_float4(val[i][0], val[i][1], val[i][2], val[i][3]);
        *(float4*)(out0 + ((size_t)(b*COUT_) + o0 + ty*4 + i) * M_ + mb) = o4;
    }
}

// ---------------------------------------------------------------------------
extern "C" void kernel_launch(void* const* d_in, const int* in_sizes, int n_in,
                              void* d_out, int out_size, void* d_ws, size_t ws_size,
                              hipStream_t stream)
{
    (void)in_sizes; (void)n_in; (void)out_size; (void)ws_size;

    const float* x1    = (const float*)d_in[0];
    const float* p1    = (const float*)d_in[1];
    const float* x2    = (const float*)d_in[2];
    const float* p2    = (const float*)d_in[3];
    const float* w_up  = (const float*)d_in[4];
    const float* g_up  = (const float*)d_in[5];
    const float* b_up  = (const float*)d_in[6];
    const float* m_up  = (const float*)d_in[7];
    const float* v_up  = (const float*)d_in[8];
    const float* w_lat = (const float*)d_in[9];
    const float* g_lat = (const float*)d_in[10];
    const float* b_lat = (const float*)d_in[11];
    const float* m_lat = (const float*)d_in[12];
    const float* v_lat = (const float*)d_in[13];

    float* out0 = (float*)d_out;
    float* out1 = out0 + (size_t)B_ * COUT_ * M_;   // p2 passthrough

    // workspace layout: f1t (8 MB) | nn_idx (384 KB) | nn_w (384 KB)
    float* f1t   = (float*)d_ws;
    int*   nn_idx = (int*)((char*)d_ws + (size_t)B_ * N_ * COUT_ * 4);
    float* nn_w   = (float*)((char*)nn_idx + (size_t)B_ * M_ * 3 * 4);

    up_conv_kernel<<<dim3(N_/64, COUT_/64, B_), 256, 0, stream>>>(
        x1, w_up, g_up, b_up, m_up, v_up, f1t);
    three_nn_kernel<<<dim3(M_/32, B_), 256, 0, stream>>>(
        p1, p2, nn_idx, nn_w, out1);
    lat_interp_kernel<<<dim3(M_/64, COUT_/64, B_), 256, 0, stream>>>(
        x2, w_lat, g_lat, b_lat, m_lat, v_lat, f1t, nn_idx, nn_w, out0);
}

// Round 7
// 178.001 us; speedup vs baseline: 2.0316x; 2.0316x over previous
//
#include <hip/hip_runtime.h>
#include <math.h>
#include <float.h>

#define B_    4
#define N_    2048
#define M_    8192
#define CIN_  512
#define COUT_ 256

// ---------------------------------------------------------------------------
// System-scope relaxed atomics for the d_ws producer->consumer handoff.
// (Round-4 post-timing divergence: 0xAA poison lines stale in consumer-XCD L2;
// sc0/sc1 ops bypass L1 + per-XCD L2 and hit the coherence point.)
// ---------------------------------------------------------------------------
__device__ __forceinline__ void ws_store_f32(float* p, float v) {
    __hip_atomic_store((unsigned int*)p, __float_as_uint(v),
                       __ATOMIC_RELAXED, __HIP_MEMORY_SCOPE_SYSTEM);
}
__device__ __forceinline__ void ws_store_u32(int* p, int v) {
    __hip_atomic_store((unsigned int*)p, (unsigned int)v,
                       __ATOMIC_RELAXED, __HIP_MEMORY_SCOPE_SYSTEM);
}
__device__ __forceinline__ float ws_load_f32(const float* p) {
    return __uint_as_float(__hip_atomic_load((const unsigned int*)p,
                       __ATOMIC_RELAXED, __HIP_MEMORY_SCOPE_SYSTEM));
}
__device__ __forceinline__ int ws_load_u32(const int* p) {
    return (int)__hip_atomic_load((const unsigned int*)p,
                       __ATOMIC_RELAXED, __HIP_MEMORY_SCOPE_SYSTEM);
}

// ---------------------------------------------------------------------------
// Kernel A: f1t[b][n][c] = relu( bn( sum_ci w_up[c,ci]*x1[b,ci,n] ) )
// ---------------------------------------------------------------------------
__global__ __launch_bounds__(256) void up_conv_kernel(
    const float* __restrict__ x1, const float* __restrict__ w,
    const float* __restrict__ gam, const float* __restrict__ bet,
    const float* __restrict__ mu, const float* __restrict__ var,
    float* __restrict__ f1t)
{
    __shared__ float sm[4224];
    float* Ws = sm;          // [32][68]  Ws[k*68 + o]
    float* Xs = sm + 2176;   // [32][64]  Xs[k*64 + n]
    const int b = blockIdx.z;
    const int o0 = blockIdx.y * 64;
    const int n0 = blockIdx.x * 64;
    const int tid = threadIdx.x;
    const int tx = tid & 15, ty = tid >> 4;

    float acc[4][4] = {{0.f}};

    for (int kc = 0; kc < CIN_; kc += 32) {
        #pragma unroll
        for (int r = 0; r < 2; ++r) {
            int e = tid + r * 256;          // 512 float4 of W tile (64o x 32k)
            int o = e >> 3, k4 = e & 7;
            float4 v = *(const float4*)(w + (size_t)(o0 + o) * CIN_ + kc + k4 * 4);
            Ws[(k4*4+0)*68 + o] = v.x;
            Ws[(k4*4+1)*68 + o] = v.y;
            Ws[(k4*4+2)*68 + o] = v.z;
            Ws[(k4*4+3)*68 + o] = v.w;
        }
        #pragma unroll
        for (int r = 0; r < 2; ++r) {
            int e = tid + r * 256;          // 512 float4 of X tile (32k x 64n)
            int k = e >> 4, c4 = e & 15;
            *(float4*)(Xs + k*64 + c4*4) =
                *(const float4*)(x1 + ((size_t)(b * CIN_ + kc + k)) * N_ + n0 + c4*4);
        }
        __syncthreads();
        #pragma unroll
        for (int k = 0; k < 32; ++k) {
            float4 av = *(const float4*)(Ws + k*68 + ty*4);
            float4 bv = *(const float4*)(Xs + k*64 + tx*4);
            float a[4] = {av.x, av.y, av.z, av.w};
            float c[4] = {bv.x, bv.y, bv.z, bv.w};
            #pragma unroll
            for (int i = 0; i < 4; ++i)
                #pragma unroll
                for (int j = 0; j < 4; ++j)
                    acc[i][j] = fmaf(a[i], c[j], acc[i][j]);
        }
        __syncthreads();
    }

    float* S = sm; // [64][65]
    #pragma unroll
    for (int i = 0; i < 4; ++i) {
        int o = o0 + ty*4 + i;
        float sc = gam[o] / sqrtf(var[o] + 1e-5f);
        float sh = bet[o] - mu[o] * sc;
        #pragma unroll
        for (int j = 0; j < 4; ++j) {
            float v = fmaxf(acc[i][j] * sc + sh, 0.0f);
            S[(tx*4+j)*65 + ty*4+i] = v;
        }
    }
    __syncthreads();
    #pragma unroll
    for (int r = 0; r < 16; ++r) {
        int e = tid + r * 256;
        int n = e >> 6, o = e & 63;
        ws_store_f32(f1t + ((size_t)(b * N_) + n0 + n) * COUT_ + o0 + o, S[n*65 + o]);
    }
}

// ---------------------------------------------------------------------------
// Kernel B: three_nn + inverse-distance weights + p2 passthrough.
// 8 lanes per query, segment s scans candidates n = 256s..256s+255 ASCENDING.
// LDS: float4 P[8][257] = (x,y,z,s1) per candidate; the 257 pad puts the 8
// segments on 8 disjoint 4-bank groups (dword 1028*s % 32 = 4s) -> one
// conflict-free broadcast ds_read_b128 per candidate, offset-immediate.
// Per-candidate: 13-instr branchless bubble-insert with strict < (ascending
// scan makes lower-index-wins automatic). Butterfly merge keeps the full
// lexicographic (d2, idx) compare. d^2 bits identical to validated rounds:
//   s   = fma(z,z, fma(y,y, x*x));  dot = fma(z,z', fma(y,y', x*x'))
//   d2  = max(fma(-2, dot, s2 + s1), 0)
// ---------------------------------------------------------------------------
__device__ __forceinline__ void lex_insert(float e, int j,
    float& D0, float& D1, float& D2, int& I0, int& I1, int& I2)
{
    bool l0 = (e < D0) || (e == D0 && j < I0);
    bool l1 = (e < D1) || (e == D1 && j < I1);
    bool l2 = (e < D2) || (e == D2 && j < I2);
    if (l2) {
        if (l0)      { D2=D1; I2=I1; D1=D0; I1=I0; D0=e; I0=j; }
        else if (l1) { D2=D1; I2=I1; D1=e;  I1=j; }
        else         { D2=e;  I2=j; }
    }
}

__device__ __forceinline__ void bubble_insert(float e, int ie,
    float& D0, float& D1, float& D2, int& I0, int& I1, int& I2)
{
    // slot 2
    bool l2 = e < D2;
    D2 = l2 ? e  : D2;
    I2 = l2 ? ie : I2;
    // sort (D1, D2)
    bool s1 = D2 < D1;
    float tf = D1; int ti = I1;
    D1 = s1 ? D2 : D1;  I1 = s1 ? I2 : I1;
    D2 = s1 ? tf : D2;  I2 = s1 ? ti : I2;
    // sort (D0, D1)
    bool s0 = D1 < D0;
    tf = D0; ti = I0;
    D0 = s0 ? D1 : D0;  I0 = s0 ? I1 : I0;
    D1 = s0 ? tf : D1;  I1 = s0 ? ti : I1;
}

__global__ __launch_bounds__(256) void three_nn_kernel(
    const float* __restrict__ p1, const float* __restrict__ p2,
    int* __restrict__ nn_idx, float* __restrict__ nn_w,
    float* __restrict__ out1)
{
    __shared__ float4 P[8][257];
    const int b = blockIdx.y;
    #pragma unroll
    for (int r = 0; r < 8; ++r) {
        int n = r * 256 + threadIdx.x;
        float x = p1[((size_t)(b*N_)+n)*3 + 0];
        float y = p1[((size_t)(b*N_)+n)*3 + 1];
        float z = p1[((size_t)(b*N_)+n)*3 + 2];
        float t = x * x;
        t = fmaf(y, y, t);
        t = fmaf(z, z, t);
        P[r][threadIdx.x] = make_float4(x, y, z, t);
    }
    __syncthreads();

    const int m = blockIdx.x * 32 + (threadIdx.x >> 3);
    const int s = threadIdx.x & 7;
    const size_t pbase = ((size_t)(b*M_) + m) * 3;
    const float qx = p2[pbase+0], qy = p2[pbase+1], qz = p2[pbase+2];
    float s2 = qx * qx;
    s2 = fmaf(qy, qy, s2);
    s2 = fmaf(qz, qz, s2);

    float D0 = FLT_MAX, D1 = FLT_MAX, D2 = FLT_MAX;
    int   I0 = 0x7fffffff, I1 = 0x7fffffff, I2 = 0x7fffffff;
    const int base = s * 256;
    const float4* Ps = &P[s][0];

    for (int t = 0; t < 256; t += 8) {
        float4 c[8];
        #pragma unroll
        for (int u = 0; u < 8; ++u) c[u] = Ps[t + u];   // b128, offset:16u
        float d[8];
        #pragma unroll
        for (int u = 0; u < 8; ++u) {
            float dot = qx * c[u].x;
            dot = fmaf(qy, c[u].y, dot);
            dot = fmaf(qz, c[u].z, dot);
            float d2 = fmaf(-2.0f, dot, s2 + c[u].w);
            d[u] = fmaxf(d2, 0.0f);
        }
        #pragma unroll
        for (int u = 0; u < 8; ++u)
            bubble_insert(d[u], base + t + u, D0, D1, D2, I0, I1, I2);
    }

    #pragma unroll
    for (int st = 1; st <= 4; st <<= 1) {
        float E0 = __shfl_xor(D0, st), E1 = __shfl_xor(D1, st), E2 = __shfl_xor(D2, st);
        int   J0 = __shfl_xor(I0, st), J1 = __shfl_xor(I1, st), J2 = __shfl_xor(I2, st);
        lex_insert(E0, J0, D0, D1, D2, I0, I1, I2);
        lex_insert(E1, J1, D0, D1, D2, I0, I1, I2);
        lex_insert(E2, J2, D0, D1, D2, I0, I1, I2);
    }
    if (s == 0) {
        float r0 = 1.0f / (D0 + 1e-8f);
        float r1 = 1.0f / (D1 + 1e-8f);
        float r2 = 1.0f / (D2 + 1e-8f);
        float sum = (r0 + r1) + r2;
        size_t o = ((size_t)(b*M_) + m) * 3;
        ws_store_u32(nn_idx + o+0, I0);
        ws_store_u32(nn_idx + o+1, I1);
        ws_store_u32(nn_idx + o+2, I2);
        ws_store_f32(nn_w + o+0, r0 / sum);
        ws_store_f32(nn_w + o+1, r1 / sum);
        ws_store_f32(nn_w + o+2, r2 / sum);
        out1[o+0] = qx; out1[o+1] = qy; out1[o+2] = qz;
    }
}

// ---------------------------------------------------------------------------
// Kernel C: out0[b][c][m] = relu(bn(sum_ci w_lat[c,ci]*x2[b,ci,m]))
//                           + sum_k nn_w[b,m,k] * f1t[b][idx[b,m,k]][c]
// ---------------------------------------------------------------------------
__global__ __launch_bounds__(256) void lat_interp_kernel(
    const float* __restrict__ x2, const float* __restrict__ w,
    const float* __restrict__ gam, const float* __restrict__ bet,
    const float* __restrict__ mu, const float* __restrict__ var,
    const float* __restrict__ f1t, const int* __restrict__ nn_idx,
    const float* __restrict__ nn_w, float* __restrict__ out0)
{
    __shared__ float sm[4224];
    float* Ws = sm;          // [32][68]
    float* Xs = sm + 2176;   // [32][64]
    const int b = blockIdx.z;
    const int o0 = blockIdx.y * 64;
    const int m0 = blockIdx.x * 64;
    const int tid = threadIdx.x;
    const int tx = tid & 15, ty = tid >> 4;

    float acc[4][4] = {{0.f}};

    for (int kc = 0; kc < COUT_; kc += 32) {
        #pragma unroll
        for (int r = 0; r < 2; ++r) {
            int e = tid + r * 256;
            int o = e >> 3, k4 = e & 7;
            float4 v = *(const float4*)(w + (size_t)(o0 + o) * COUT_ + kc + k4 * 4);
            Ws[(k4*4+0)*68 + o] = v.x;
            Ws[(k4*4+1)*68 + o] = v.y;
            Ws[(k4*4+2)*68 + o] = v.z;
            Ws[(k4*4+3)*68 + o] = v.w;
        }
        #pragma unroll
        for (int r = 0; r < 2; ++r) {
            int e = tid + r * 256;
            int k = e >> 4, c4 = e & 15;
            *(float4*)(Xs + k*64 + c4*4) =
                *(const float4*)(x2 + ((size_t)(b * COUT_ + kc + k)) * M_ + m0 + c4*4);
        }
        __syncthreads();
        #pragma unroll
        for (int k = 0; k < 32; ++k) {
            float4 av = *(const float4*)(Ws + k*68 + ty*4);
            float4 bv = *(const float4*)(Xs + k*64 + tx*4);
            float a[4] = {av.x, av.y, av.z, av.w};
            float c[4] = {bv.x, bv.y, bv.z, bv.w};
            #pragma unroll
            for (int i = 0; i < 4; ++i)
                #pragma unroll
                for (int j = 0; j < 4; ++j)
                    acc[i][j] = fmaf(a[i], c[j], acc[i][j]);
        }
        __syncthreads();
    }

    const int mb = m0 + tx * 4;
    int   idx[4][3];
    float wq[4][3];
    #pragma unroll
    for (int j = 0; j < 4; ++j)
        #pragma unroll
        for (int k = 0; k < 3; ++k) {
            size_t o = ((size_t)(b*M_) + mb + j) * 3 + k;
            idx[j][k] = ws_load_u32(nn_idx + o);
            wq[j][k]  = ws_load_f32(nn_w + o);
        }

    float val[4][4];
    #pragma unroll
    for (int i = 0; i < 4; ++i) {
        int c = o0 + ty*4 + i;
        float sc = gam[c] / sqrtf(var[c] + 1e-5f);
        float sh = bet[c] - mu[c] * sc;
        #pragma unroll
        for (int j = 0; j < 4; ++j)
            val[i][j] = fmaxf(acc[i][j] * sc + sh, 0.0f);
    }
    #pragma unroll
    for (int j = 0; j < 4; ++j)
        #pragma unroll
        for (int k = 0; k < 3; ++k) {
            const float* gp = f1t + ((size_t)(b*N_) + idx[j][k]) * COUT_ + o0 + ty*4;
            float wk = wq[j][k];
            val[0][j] = fmaf(wk, ws_load_f32(gp + 0), val[0][j]);
            val[1][j] = fmaf(wk, ws_load_f32(gp + 1), val[1][j]);
            val[2][j] = fmaf(wk, ws_load_f32(gp + 2), val[2][j]);
            val[3][j] = fmaf(wk, ws_load_f32(gp + 3), val[3][j]);
        }
    #pragma unroll
    for (int i = 0; i < 4; ++i) {
        float4 o4 = make_float4(val[i][0], val[i][1], val[i][2], val[i][3]);
        *(float4*)(out0 + ((size_t)(b*COUT_) + o0 + ty*4 + i) * M_ + mb) = o4;
    }
}

// ---------------------------------------------------------------------------
extern "C" void kernel_launch(void* const* d_in, const int* in_sizes, int n_in,
                              void* d_out, int out_size, void* d_ws, size_t ws_size,
                              hipStream_t stream)
{
    (void)in_sizes; (void)n_in; (void)out_size; (void)ws_size;

    const float* x1    = (const float*)d_in[0];
    const float* p1    = (const float*)d_in[1];
    const float* x2    = (const float*)d_in[2];
    const float* p2    = (const float*)d_in[3];
    const float* w_up  = (const float*)d_in[4];
    const float* g_up  = (const float*)d_in[5];
    const float* b_up  = (const float*)d_in[6];
    const float* m_up  = (const float*)d_in[7];
    const float* v_up  = (const float*)d_in[8];
    const float* w_lat = (const float*)d_in[9];
    const float* g_lat = (const float*)d_in[10];
    const float* b_lat = (const float*)d_in[11];
    const float* m_lat = (const float*)d_in[12];
    const float* v_lat = (const float*)d_in[13];

    float* out0 = (float*)d_out;
    float* out1 = out0 + (size_t)B_ * COUT_ * M_;   // p2 passthrough

    // workspace layout: f1t (8 MB) | nn_idx (384 KB) | nn_w (384 KB)
    float* f1t   = (float*)d_ws;
    int*   nn_idx = (int*)((char*)d_ws + (size_t)B_ * N_ * COUT_ * 4);
    float* nn_w   = (float*)((char*)nn_idx + (size_t)B_ * M_ * 3 * 4);

    up_conv_kernel<<<dim3(N_/64, COUT_/64, B_), 256, 0, stream>>>(
        x1, w_up, g_up, b_up, m_up, v_up, f1t);
    three_nn_kernel<<<dim3(M_/32, B_), 256, 0, stream>>>(
        p1, p2, nn_idx, nn_w, out1);
    lat_interp_kernel<<<dim3(M_/64, COUT_/64, B_), 256, 0, stream>>>(
        x2, w_lat, g_lat, b_lat, m_lat, v_lat, f1t, nn_idx, nn_w, out0);
}

// Round 8
// 124.870 us; speedup vs baseline: 2.8960x; 1.4255x over previous
//
#include <hip/hip_runtime.h>
#include <math.h>
#include <float.h>

#define B_    4
#define N_    2048
#define M_    8192
#define CIN_  512
#define COUT_ 256

typedef __attribute__((ext_vector_type(8))) short short8v;   // 8 bf16
typedef __attribute__((ext_vector_type(4))) float f32x4;

// ---------------------------------------------------------------------------
// System-scope relaxed atomics for the d_ws producer->consumer handoff.
// (Round-4 post-timing divergence: 0xAA poison lines stale in consumer-XCD L2;
// sc0/sc1 ops bypass L1 + per-XCD L2 and hit the coherence point.)
// ---------------------------------------------------------------------------
__device__ __forceinline__ void ws_store_f32(float* p, float v) {
    __hip_atomic_store((unsigned int*)p, __float_as_uint(v),
                       __ATOMIC_RELAXED, __HIP_MEMORY_SCOPE_SYSTEM);
}
__device__ __forceinline__ void ws_store_u32(int* p, int v) {
    __hip_atomic_store((unsigned int*)p, (unsigned int)v,
                       __ATOMIC_RELAXED, __HIP_MEMORY_SCOPE_SYSTEM);
}
__device__ __forceinline__ float ws_load_f32(const float* p) {
    return __uint_as_float(__hip_atomic_load((const unsigned int*)p,
                       __ATOMIC_RELAXED, __HIP_MEMORY_SCOPE_SYSTEM));
}
__device__ __forceinline__ int ws_load_u32(const int* p) {
    return (int)__hip_atomic_load((const unsigned int*)p,
                       __ATOMIC_RELAXED, __HIP_MEMORY_SCOPE_SYSTEM);
}

__device__ __forceinline__ unsigned short f2bf(float f) {   // RNE f32->bf16
    unsigned u = __float_as_uint(f);
    u += 0x7fffu + ((u >> 16) & 1u);
    return (unsigned short)(u >> 16);
}

// ---------------------------------------------------------------------------
// Templated bf16-MFMA GEMM: out[c][m] = sum_k W[c][k] * X[k][m]  (per batch)
// Block tile 128c x 128m, 4 waves (2c x 2m), wave tile 64x64 (4x4 MFMA accs),
// K-steps of 32 (one mfma_f32_16x16x32_bf16 per 16x16 tile per step).
// fp32->bf16 conversion happens during LDS staging.
// LDS rows padded to 40 bf16 (80 B = 5*16 B): frag b128 reads bank-balanced
// and 16B-aligned; A/B share the SAME lane->k mapping so any common k
// permutation cancels inside the MFMA dot product (layout-safe).
// MODE 0 (up):  epilogue BN+ReLU -> LDS transpose -> sc-stores f1t[n][c]
// MODE 1 (lat): epilogue BN+ReLU + 3-NN interp add -> stores out0[c][m]
// ---------------------------------------------------------------------------
template<int K, int MODE>
__global__ __launch_bounds__(256) void gemm_bf16_kernel(
    const float* __restrict__ X, const float* __restrict__ W,
    const float* __restrict__ gam, const float* __restrict__ bet,
    const float* __restrict__ mu, const float* __restrict__ var,
    float* __restrict__ dst,
    const float* __restrict__ f1t, const int* __restrict__ nn_idx,
    const float* __restrict__ nn_w, int Mdim)
{
    constexpr int LDSB = (MODE == 0) ? 34080 : 20480;
    __shared__ char raw[LDSB];
    char* Ab = raw;            // A: [128 c][40 bf16]  row stride 80 B
    char* Bb = raw + 10240;    // B: [128 m][40 bf16]

    const int b  = blockIdx.z;
    const int c0 = blockIdx.y * 128;
    const int m0 = blockIdx.x * 128;
    const int tid = threadIdx.x;
    const int l  = tid & 63;
    const int wv = tid >> 6;
    const int wc = wv & 1, wn = wv >> 1;

    f32x4 acc[4][4];
    #pragma unroll
    for (int i = 0; i < 4; ++i)
        #pragma unroll
        for (int j = 0; j < 4; ++j)
            acc[i][j] = (f32x4){0.f, 0.f, 0.f, 0.f};

    const int ksA = tid & 7;          // k-seg for A staging (float4 along k)
    const int crA = tid >> 3;         // c 0..31 (+32r)
    const int kqB = tid >> 5;         // k-quad 0..7 for B staging
    const int mlB = tid & 31;         // m lane (+32jj)

    for (int kc = 0; kc < K; kc += 32) {
        // ---- stage A (W is [c][k], k contiguous): no transpose ----
        #pragma unroll
        for (int r = 0; r < 4; ++r) {
            int c = crA + 32 * r;
            float4 v = *(const float4*)(W + (size_t)(c0 + c) * K + kc + ksA * 4);
            unsigned lo = f2bf(v.x) | ((unsigned)f2bf(v.y) << 16);
            unsigned hi = f2bf(v.z) | ((unsigned)f2bf(v.w) << 16);
            *(uint2*)(Ab + c * 80 + ksA * 8) = make_uint2(lo, hi);
        }
        // ---- stage B (X is [k][m], m contiguous): transpose to [m][k] ----
        // per thread: 4 m values (stride 32 -> conflict-free b64 writes),
        // 4 adjacent k each (coalesced scalar global reads per row).
        #pragma unroll
        for (int jj = 0; jj < 4; ++jj) {
            int m = mlB + 32 * jj;
            const float* xp = X + ((size_t)b * K + kc + kqB * 4) * Mdim + m0 + m;
            float v0 = xp[0];
            float v1 = xp[(size_t)Mdim];
            float v2 = xp[(size_t)2 * Mdim];
            float v3 = xp[(size_t)3 * Mdim];
            unsigned lo = f2bf(v0) | ((unsigned)f2bf(v1) << 16);
            unsigned hi = f2bf(v2) | ((unsigned)f2bf(v3) << 16);
            *(uint2*)(Bb + m * 80 + kqB * 8) = make_uint2(lo, hi);
        }
        __syncthreads();
        // ---- fragments + MFMA ----
        short8v a[4], bf[4];
        #pragma unroll
        for (int ci = 0; ci < 4; ++ci)
            a[ci] = *(const short8v*)(Ab + (wc * 64 + ci * 16 + (l & 15)) * 80 + (l >> 4) * 16);
        #pragma unroll
        for (int ni = 0; ni < 4; ++ni)
            bf[ni] = *(const short8v*)(Bb + (wn * 64 + ni * 16 + (l & 15)) * 80 + (l >> 4) * 16);
        #pragma unroll
        for (int ci = 0; ci < 4; ++ci)
            #pragma unroll
            for (int ni = 0; ni < 4; ++ni)
                acc[ci][ni] = __builtin_amdgcn_mfma_f32_16x16x32_bf16(
                    a[ci], bf[ni], acc[ci][ni], 0, 0, 0);
        __syncthreads();
    }

    // BN scale/shift per (ci, reg): c = c0 + wc*64 + ci*16 + (l>>4)*4 + r
    const int lc = (l >> 4) * 4;
    float scA[4][4], shA[4][4];
    #pragma unroll
    for (int ci = 0; ci < 4; ++ci)
        #pragma unroll
        for (int r = 0; r < 4; ++r) {
            int c = c0 + wc * 64 + ci * 16 + lc + r;
            float sc = gam[c] / sqrtf(var[c] + 1e-5f);
            scA[ci][r] = sc;
            shA[ci][r] = bet[c] - mu[c] * sc;
        }

    if constexpr (MODE == 0) {
        // transpose 64 n-rows at a time through LDS, sc-store f1t[n][c]
        float* S = (float*)raw;   // [64][133] f32
        #pragma unroll
        for (int h = 0; h < 2; ++h) {
            if (wn == h) {
                #pragma unroll
                for (int ni = 0; ni < 4; ++ni)
                    #pragma unroll
                    for (int ci = 0; ci < 4; ++ci)
                        #pragma unroll
                        for (int r = 0; r < 4; ++r)
                            S[(ni * 16 + (l & 15)) * 133 + wc * 64 + ci * 16 + lc + r] =
                                fmaxf(acc[ci][ni][r] * scA[ci][r] + shA[ci][r], 0.f);
            }
            __syncthreads();
            #pragma unroll
            for (int i = 0; i < 32; ++i) {
                int e = tid + i * 256;
                int row = e >> 7, c = e & 127;
                ws_store_f32(dst + ((size_t)b * N_ + m0 + h * 64 + row) * COUT_ + c0 + c,
                             S[row * 133 + c]);
            }
            __syncthreads();
        }
    } else {
        // lat: BN+ReLU + inverse-distance interp add, store out0[c][m]
        #pragma unroll
        for (int ni = 0; ni < 4; ++ni) {
            int mg = m0 + wn * 64 + ni * 16 + (l & 15);
            size_t io = ((size_t)b * M_ + mg) * 3;
            int   i0 = ws_load_u32(nn_idx + io + 0);
            int   i1 = ws_load_u32(nn_idx + io + 1);
            int   i2 = ws_load_u32(nn_idx + io + 2);
            float w0 = ws_load_f32(nn_w + io + 0);
            float w1 = ws_load_f32(nn_w + io + 1);
            float w2 = ws_load_f32(nn_w + io + 2);
            const float* g0 = f1t + ((size_t)b * N_ + i0) * COUT_ + c0 + wc * 64 + lc;
            const float* g1 = f1t + ((size_t)b * N_ + i1) * COUT_ + c0 + wc * 64 + lc;
            const float* g2 = f1t + ((size_t)b * N_ + i2) * COUT_ + c0 + wc * 64 + lc;
            #pragma unroll
            for (int ci = 0; ci < 4; ++ci) {
                #pragma unroll
                for (int r = 0; r < 4; ++r) {
                    float v = fmaxf(acc[ci][ni][r] * scA[ci][r] + shA[ci][r], 0.f);
                    v = fmaf(w0, ws_load_f32(g0 + ci * 16 + r), v);
                    v = fmaf(w1, ws_load_f32(g1 + ci * 16 + r), v);
                    v = fmaf(w2, ws_load_f32(g2 + ci * 16 + r), v);
                    int c = c0 + wc * 64 + ci * 16 + lc + r;
                    dst[((size_t)b * COUT_ + c) * M_ + mg] = v;
                }
            }
        }
    }
}

// ---------------------------------------------------------------------------
// Kernel B: three_nn + inverse-distance weights + p2 passthrough (round 7,
// unchanged): 8 lanes/query, b128 broadcast candidate reads, branchless
// bubble-insert, butterfly lex-merge. d^2 bits identical to validated rounds.
// ---------------------------------------------------------------------------
__device__ __forceinline__ void lex_insert(float e, int j,
    float& D0, float& D1, float& D2, int& I0, int& I1, int& I2)
{
    bool l0 = (e < D0) || (e == D0 && j < I0);
    bool l1 = (e < D1) || (e == D1 && j < I1);
    bool l2 = (e < D2) || (e == D2 && j < I2);
    if (l2) {
        if (l0)      { D2=D1; I2=I1; D1=D0; I1=I0; D0=e; I0=j; }
        else if (l1) { D2=D1; I2=I1; D1=e;  I1=j; }
        else         { D2=e;  I2=j; }
    }
}

__device__ __forceinline__ void bubble_insert(float e, int ie,
    float& D0, float& D1, float& D2, int& I0, int& I1, int& I2)
{
    bool l2 = e < D2;
    D2 = l2 ? e  : D2;
    I2 = l2 ? ie : I2;
    bool s1 = D2 < D1;
    float tf = D1; int ti = I1;
    D1 = s1 ? D2 : D1;  I1 = s1 ? I2 : I1;
    D2 = s1 ? tf : D2;  I2 = s1 ? ti : I2;
    bool s0 = D1 < D0;
    tf = D0; ti = I0;
    D0 = s0 ? D1 : D0;  I0 = s0 ? I1 : I0;
    D1 = s0 ? tf : D1;  I1 = s0 ? ti : I1;
}

__global__ __launch_bounds__(256) void three_nn_kernel(
    const float* __restrict__ p1, const float* __restrict__ p2,
    int* __restrict__ nn_idx, float* __restrict__ nn_w,
    float* __restrict__ out1)
{
    __shared__ float4 P[8][257];
    const int b = blockIdx.y;
    #pragma unroll
    for (int r = 0; r < 8; ++r) {
        int n = r * 256 + threadIdx.x;
        float x = p1[((size_t)(b*N_)+n)*3 + 0];
        float y = p1[((size_t)(b*N_)+n)*3 + 1];
        float z = p1[((size_t)(b*N_)+n)*3 + 2];
        float t = x * x;
        t = fmaf(y, y, t);
        t = fmaf(z, z, t);
        P[r][threadIdx.x] = make_float4(x, y, z, t);
    }
    __syncthreads();

    const int m = blockIdx.x * 32 + (threadIdx.x >> 3);
    const int s = threadIdx.x & 7;
    const size_t pbase = ((size_t)(b*M_) + m) * 3;
    const float qx = p2[pbase+0], qy = p2[pbase+1], qz = p2[pbase+2];
    float s2 = qx * qx;
    s2 = fmaf(qy, qy, s2);
    s2 = fmaf(qz, qz, s2);

    float D0 = FLT_MAX, D1 = FLT_MAX, D2 = FLT_MAX;
    int   I0 = 0x7fffffff, I1 = 0x7fffffff, I2 = 0x7fffffff;
    const int base = s * 256;
    const float4* Ps = &P[s][0];

    for (int t = 0; t < 256; t += 8) {
        float4 c[8];
        #pragma unroll
        for (int u = 0; u < 8; ++u) c[u] = Ps[t + u];
        float d[8];
        #pragma unroll
        for (int u = 0; u < 8; ++u) {
            float dot = qx * c[u].x;
            dot = fmaf(qy, c[u].y, dot);
            dot = fmaf(qz, c[u].z, dot);
            float d2 = fmaf(-2.0f, dot, s2 + c[u].w);
            d[u] = fmaxf(d2, 0.0f);
        }
        #pragma unroll
        for (int u = 0; u < 8; ++u)
            bubble_insert(d[u], base + t + u, D0, D1, D2, I0, I1, I2);
    }

    #pragma unroll
    for (int st = 1; st <= 4; st <<= 1) {
        float E0 = __shfl_xor(D0, st), E1 = __shfl_xor(D1, st), E2 = __shfl_xor(D2, st);
        int   J0 = __shfl_xor(I0, st), J1 = __shfl_xor(I1, st), J2 = __shfl_xor(I2, st);
        lex_insert(E0, J0, D0, D1, D2, I0, I1, I2);
        lex_insert(E1, J1, D0, D1, D2, I0, I1, I2);
        lex_insert(E2, J2, D0, D1, D2, I0, I1, I2);
    }
    if (s == 0) {
        float r0 = 1.0f / (D0 + 1e-8f);
        float r1 = 1.0f / (D1 + 1e-8f);
        float r2 = 1.0f / (D2 + 1e-8f);
        float sum = (r0 + r1) + r2;
        size_t o = ((size_t)(b*M_) + m) * 3;
        ws_store_u32(nn_idx + o+0, I0);
        ws_store_u32(nn_idx + o+1, I1);
        ws_store_u32(nn_idx + o+2, I2);
        ws_store_f32(nn_w + o+0, r0 / sum);
        ws_store_f32(nn_w + o+1, r1 / sum);
        ws_store_f32(nn_w + o+2, r2 / sum);
        out1[o+0] = qx; out1[o+1] = qy; out1[o+2] = qz;
    }
}

// ---------------------------------------------------------------------------
extern "C" void kernel_launch(void* const* d_in, const int* in_sizes, int n_in,
                              void* d_out, int out_size, void* d_ws, size_t ws_size,
                              hipStream_t stream)
{
    (void)in_sizes; (void)n_in; (void)out_size; (void)ws_size;

    const float* x1    = (const float*)d_in[0];
    const float* p1    = (const float*)d_in[1];
    const float* x2    = (const float*)d_in[2];
    const float* p2    = (const float*)d_in[3];
    const float* w_up  = (const float*)d_in[4];
    const float* g_up  = (const float*)d_in[5];
    const float* b_up  = (const float*)d_in[6];
    const float* m_up  = (const float*)d_in[7];
    const float* v_up  = (const float*)d_in[8];
    const float* w_lat = (const float*)d_in[9];
    const float* g_lat = (const float*)d_in[10];
    const float* b_lat = (const float*)d_in[11];
    const float* m_lat = (const float*)d_in[12];
    const float* v_lat = (const float*)d_in[13];

    float* out0 = (float*)d_out;
    float* out1 = out0 + (size_t)B_ * COUT_ * M_;   // p2 passthrough

    // workspace layout: f1t (8 MB) | nn_idx (384 KB) | nn_w (384 KB)
    float* f1t   = (float*)d_ws;
    int*   nn_idx = (int*)((char*)d_ws + (size_t)B_ * N_ * COUT_ * 4);
    float* nn_w   = (float*)((char*)nn_idx + (size_t)B_ * M_ * 3 * 4);

    // up branch: f1t[n][c] via MFMA GEMM (K=512), MODE 0 epilogue
    gemm_bf16_kernel<CIN_, 0><<<dim3(N_ / 128, COUT_ / 128, B_), 256, 0, stream>>>(
        x1, w_up, g_up, b_up, m_up, v_up, f1t, nullptr, nullptr, nullptr, N_);

    three_nn_kernel<<<dim3(M_ / 32, B_), 256, 0, stream>>>(
        p1, p2, nn_idx, nn_w, out1);

    // lateral + interp: out0[c][m] via MFMA GEMM (K=256), MODE 1 epilogue
    gemm_bf16_kernel<COUT_, 1><<<dim3(M_ / 128, COUT_ / 128, B_), 256, 0, stream>>>(
        x2, w_lat, g_lat, b_lat, m_lat, v_lat, out0, f1t, nn_idx, nn_w, M_);
}

// Round 9
// 115.427 us; speedup vs baseline: 3.1329x; 1.0818x over previous
//
#include <hip/hip_runtime.h>
#include <math.h>
#include <float.h>

#define B_    4
#define N_    2048
#define M_    8192
#define CIN_  512
#define COUT_ 256

typedef __attribute__((ext_vector_type(8))) short short8v;   // 8 bf16
typedef __attribute__((ext_vector_type(4))) float f32x4;

// ---------------------------------------------------------------------------
// Producer side of the d_ws handoff: system-scope stores (sc0 sc1) write
// through to the L3 coherence point. Consumer side: `buffer_inv sc0 sc1` at
// kernel entry invalidates the XCD's stale L1/L2 lines (0xAA poison), after
// which NORMAL cached loads are safe and L2-cacheable. (Round-4 post-timing
// divergence root cause; round-8 showed sc-loads are a 500-cyc/dword tax.)
// ---------------------------------------------------------------------------
__device__ __forceinline__ void ws_store_f32(float* p, float v) {
    __hip_atomic_store((unsigned int*)p, __float_as_uint(v),
                       __ATOMIC_RELAXED, __HIP_MEMORY_SCOPE_SYSTEM);
}
__device__ __forceinline__ void ws_store_u32(int* p, int v) {
    __hip_atomic_store((unsigned int*)p, (unsigned int)v,
                       __ATOMIC_RELAXED, __HIP_MEMORY_SCOPE_SYSTEM);
}
__device__ __forceinline__ void l2_invalidate() {
    asm volatile("buffer_inv sc0 sc1" ::: "memory");
}

__device__ __forceinline__ unsigned short f2bf(float f) {   // RNE f32->bf16
    unsigned u = __float_as_uint(f);
    u += 0x7fffu + ((u >> 16) & 1u);
    return (unsigned short)(u >> 16);
}

// ---------------------------------------------------------------------------
// bf16-MFMA GEMM body: out[c][m] = sum_k W[c][k] * X[k][m]  (per batch)
// Block tile 128c x 128m, 4 waves (2c x 2m), wave tile 64x64 (4x4 MFMA accs),
// K-steps of 32 (mfma_f32_16x16x32_bf16). fp32->bf16 RNE during LDS staging.
// LDS rows padded to 40 bf16 (80 B): b128 frag reads bank-balanced + aligned;
// A/B share the same lane->k mapping (common k-permutation cancels in MFMA).
// MODE 0 (up):  BN+ReLU -> LDS transpose -> sc-stores f1t[n][c]
// MODE 1 (lat): BN+ReLU + 3-NN interp add (normal float4 gathers) -> out0
// ---------------------------------------------------------------------------
template<int K, int MODE>
__device__ __forceinline__ void gemm_body(
    char* raw, int b, int c0, int m0,
    const float* __restrict__ X, const float* __restrict__ W,
    const float* __restrict__ gam, const float* __restrict__ bet,
    const float* __restrict__ mu, const float* __restrict__ var,
    float* __restrict__ dst,
    const float* __restrict__ f1t, const int* __restrict__ nn_idx,
    const float* __restrict__ nn_w, int Mdim)
{
    char* Ab = raw;            // A: [128 c][40 bf16]  row stride 80 B
    char* Bb = raw + 10240;    // B: [128 m][40 bf16]

    const int tid = threadIdx.x;
    const int l  = tid & 63;
    const int wv = tid >> 6;
    const int wc = wv & 1, wn = wv >> 1;

    f32x4 acc[4][4];
    #pragma unroll
    for (int i = 0; i < 4; ++i)
        #pragma unroll
        for (int j = 0; j < 4; ++j)
            acc[i][j] = (f32x4){0.f, 0.f, 0.f, 0.f};

    const int ksA = tid & 7;          // k-seg for A staging (float4 along k)
    const int crA = tid >> 3;         // c 0..31 (+32r)
    const int kqB = tid >> 5;         // k-quad 0..7 for B staging
    const int mlB = tid & 31;         // m lane (+32jj)

    for (int kc = 0; kc < K; kc += 32) {
        #pragma unroll
        for (int r = 0; r < 4; ++r) {
            int c = crA + 32 * r;
            float4 v = *(const float4*)(W + (size_t)(c0 + c) * K + kc + ksA * 4);
            unsigned lo = f2bf(v.x) | ((unsigned)f2bf(v.y) << 16);
            unsigned hi = f2bf(v.z) | ((unsigned)f2bf(v.w) << 16);
            *(uint2*)(Ab + c * 80 + ksA * 8) = make_uint2(lo, hi);
        }
        #pragma unroll
        for (int jj = 0; jj < 4; ++jj) {
            int m = mlB + 32 * jj;
            const float* xp = X + ((size_t)b * K + kc + kqB * 4) * Mdim + m0 + m;
            float v0 = xp[0];
            float v1 = xp[(size_t)Mdim];
            float v2 = xp[(size_t)2 * Mdim];
            float v3 = xp[(size_t)3 * Mdim];
            unsigned lo = f2bf(v0) | ((unsigned)f2bf(v1) << 16);
            unsigned hi = f2bf(v2) | ((unsigned)f2bf(v3) << 16);
            *(uint2*)(Bb + m * 80 + kqB * 8) = make_uint2(lo, hi);
        }
        __syncthreads();
        short8v a[4], bf[4];
        #pragma unroll
        for (int ci = 0; ci < 4; ++ci)
            a[ci] = *(const short8v*)(Ab + (wc * 64 + ci * 16 + (l & 15)) * 80 + (l >> 4) * 16);
        #pragma unroll
        for (int ni = 0; ni < 4; ++ni)
            bf[ni] = *(const short8v*)(Bb + (wn * 64 + ni * 16 + (l & 15)) * 80 + (l >> 4) * 16);
        #pragma unroll
        for (int ci = 0; ci < 4; ++ci)
            #pragma unroll
            for (int ni = 0; ni < 4; ++ni)
                acc[ci][ni] = __builtin_amdgcn_mfma_f32_16x16x32_bf16(
                    a[ci], bf[ni], acc[ci][ni], 0, 0, 0);
        __syncthreads();
    }

    const int lc = (l >> 4) * 4;
    float scA[4][4], shA[4][4];
    #pragma unroll
    for (int ci = 0; ci < 4; ++ci)
        #pragma unroll
        for (int r = 0; r < 4; ++r) {
            int c = c0 + wc * 64 + ci * 16 + lc + r;
            float sc = gam[c] / sqrtf(var[c] + 1e-5f);
            scA[ci][r] = sc;
            shA[ci][r] = bet[c] - mu[c] * sc;
        }

    if constexpr (MODE == 0) {
        float* S = (float*)raw;   // [64][133] f32
        #pragma unroll
        for (int h = 0; h < 2; ++h) {
            if (wn == h) {
                #pragma unroll
                for (int ni = 0; ni < 4; ++ni)
                    #pragma unroll
                    for (int ci = 0; ci < 4; ++ci)
                        #pragma unroll
                        for (int r = 0; r < 4; ++r)
                            S[(ni * 16 + (l & 15)) * 133 + wc * 64 + ci * 16 + lc + r] =
                                fmaxf(acc[ci][ni][r] * scA[ci][r] + shA[ci][r], 0.f);
            }
            __syncthreads();
            #pragma unroll
            for (int i = 0; i < 32; ++i) {
                int e = tid + i * 256;
                int row = e >> 7, c = e & 127;
                ws_store_f32(dst + ((size_t)b * N_ + m0 + h * 64 + row) * COUT_ + c0 + c,
                             S[row * 133 + c]);
            }
            __syncthreads();
        }
    } else {
        // lat: BN+ReLU + interp add; NORMAL cached loads (L2 was invalidated
        // at kernel entry, f1t/nn_* correct at L3 via producer sc stores).
        #pragma unroll
        for (int ni = 0; ni < 4; ++ni) {
            int mg = m0 + wn * 64 + ni * 16 + (l & 15);
            size_t io = ((size_t)b * M_ + mg) * 3;
            int   i0 = nn_idx[io + 0];
            int   i1 = nn_idx[io + 1];
            int   i2 = nn_idx[io + 2];
            float w0 = nn_w[io + 0];
            float w1 = nn_w[io + 1];
            float w2 = nn_w[io + 2];
            const float4* g0 = (const float4*)(f1t + ((size_t)b * N_ + i0) * COUT_ + c0 + wc * 64 + lc);
            const float4* g1 = (const float4*)(f1t + ((size_t)b * N_ + i1) * COUT_ + c0 + wc * 64 + lc);
            const float4* g2 = (const float4*)(f1t + ((size_t)b * N_ + i2) * COUT_ + c0 + wc * 64 + lc);
            #pragma unroll
            for (int ci = 0; ci < 4; ++ci) {
                float4 G0 = g0[ci * 4];
                float4 G1 = g1[ci * 4];
                float4 G2 = g2[ci * 4];
                const float* f0 = (const float*)&G0;
                const float* f1 = (const float*)&G1;
                const float* f2 = (const float*)&G2;
                #pragma unroll
                for (int r = 0; r < 4; ++r) {
                    float v = fmaxf(acc[ci][ni][r] * scA[ci][r] + shA[ci][r], 0.f);
                    v = fmaf(w0, f0[r], v);
                    v = fmaf(w1, f1[r], v);
                    v = fmaf(w2, f2[r], v);
                    int c = c0 + wc * 64 + ci * 16 + lc + r;
                    dst[((size_t)b * COUT_ + c) * M_ + mg] = v;
                }
            }
        }
    }
}

// ---------------------------------------------------------------------------
// three_nn body (round-7 structure, validated): 8 lanes/query, b128 broadcast
// candidate reads from padded LDS, branchless bubble-insert, butterfly
// lex-merge. d^2 bits identical to validated rounds:
//   s = fma(z,z, fma(y,y, x*x)); dot likewise; d2 = max(fma(-2,dot,s2+s1),0)
// ---------------------------------------------------------------------------
__device__ __forceinline__ void lex_insert(float e, int j,
    float& D0, float& D1, float& D2, int& I0, int& I1, int& I2)
{
    bool l0 = (e < D0) || (e == D0 && j < I0);
    bool l1 = (e < D1) || (e == D1 && j < I1);
    bool l2 = (e < D2) || (e == D2 && j < I2);
    if (l2) {
        if (l0)      { D2=D1; I2=I1; D1=D0; I1=I0; D0=e; I0=j; }
        else if (l1) { D2=D1; I2=I1; D1=e;  I1=j; }
        else         { D2=e;  I2=j; }
    }
}

__device__ __forceinline__ void bubble_insert(float e, int ie,
    float& D0, float& D1, float& D2, int& I0, int& I1, int& I2)
{
    bool l2 = e < D2;
    D2 = l2 ? e  : D2;
    I2 = l2 ? ie : I2;
    bool s1 = D2 < D1;
    float tf = D1; int ti = I1;
    D1 = s1 ? D2 : D1;  I1 = s1 ? I2 : I1;
    D2 = s1 ? tf : D2;  I2 = s1 ? ti : I2;
    bool s0 = D1 < D0;
    tf = D0; ti = I0;
    D0 = s0 ? D1 : D0;  I0 = s0 ? I1 : I0;
    D1 = s0 ? tf : D1;  I1 = s0 ? ti : I1;
}

__device__ __forceinline__ void three_nn_body(
    float4 (*P)[257], int b, int mb,
    const float* __restrict__ p1, const float* __restrict__ p2,
    int* __restrict__ nn_idx, float* __restrict__ nn_w,
    float* __restrict__ out1)
{
    #pragma unroll
    for (int r = 0; r < 8; ++r) {
        int n = r * 256 + threadIdx.x;
        float x = p1[((size_t)(b*N_)+n)*3 + 0];
        float y = p1[((size_t)(b*N_)+n)*3 + 1];
        float z = p1[((size_t)(b*N_)+n)*3 + 2];
        float t = x * x;
        t = fmaf(y, y, t);
        t = fmaf(z, z, t);
        P[r][threadIdx.x] = make_float4(x, y, z, t);
    }
    __syncthreads();

    const int m = mb * 32 + (threadIdx.x >> 3);
    const int s = threadIdx.x & 7;
    const size_t pbase = ((size_t)(b*M_) + m) * 3;
    const float qx = p2[pbase+0], qy = p2[pbase+1], qz = p2[pbase+2];
    float s2 = qx * qx;
    s2 = fmaf(qy, qy, s2);
    s2 = fmaf(qz, qz, s2);

    float D0 = FLT_MAX, D1 = FLT_MAX, D2 = FLT_MAX;
    int   I0 = 0x7fffffff, I1 = 0x7fffffff, I2 = 0x7fffffff;
    const int base = s * 256;
    const float4* Ps = &P[s][0];

    for (int t = 0; t < 256; t += 8) {
        float4 c[8];
        #pragma unroll
        for (int u = 0; u < 8; ++u) c[u] = Ps[t + u];
        float d[8];
        #pragma unroll
        for (int u = 0; u < 8; ++u) {
            float dot = qx * c[u].x;
            dot = fmaf(qy, c[u].y, dot);
            dot = fmaf(qz, c[u].z, dot);
            float d2 = fmaf(-2.0f, dot, s2 + c[u].w);
            d[u] = fmaxf(d2, 0.0f);
        }
        #pragma unroll
        for (int u = 0; u < 8; ++u)
            bubble_insert(d[u], base + t + u, D0, D1, D2, I0, I1, I2);
    }

    #pragma unroll
    for (int st = 1; st <= 4; st <<= 1) {
        float E0 = __shfl_xor(D0, st), E1 = __shfl_xor(D1, st), E2 = __shfl_xor(D2, st);
        int   J0 = __shfl_xor(I0, st), J1 = __shfl_xor(I1, st), J2 = __shfl_xor(I2, st);
        lex_insert(E0, J0, D0, D1, D2, I0, I1, I2);
        lex_insert(E1, J1, D0, D1, D2, I0, I1, I2);
        lex_insert(E2, J2, D0, D1, D2, I0, I1, I2);
    }
    if (s == 0) {
        float r0 = 1.0f / (D0 + 1e-8f);
        float r1 = 1.0f / (D1 + 1e-8f);
        float r2 = 1.0f / (D2 + 1e-8f);
        float sum = (r0 + r1) + r2;
        size_t o = ((size_t)(b*M_) + m) * 3;
        ws_store_u32(nn_idx + o+0, I0);
        ws_store_u32(nn_idx + o+1, I1);
        ws_store_u32(nn_idx + o+2, I2);
        ws_store_f32(nn_w + o+0, r0 / sum);
        ws_store_f32(nn_w + o+1, r1 / sum);
        ws_store_f32(nn_w + o+2, r2 / sum);
        out1[o+0] = qx; out1[o+1] = qy; out1[o+2] = qz;
    }
}

// ---------------------------------------------------------------------------
// Fused dispatch 1: blocks [0,128) run the up-branch GEMM (MODE 0),
// blocks [128,1152) run three_nn. Independent work -> true overlap.
// ---------------------------------------------------------------------------
__global__ __launch_bounds__(256) void up_nn_kernel(
    const float* __restrict__ x1, const float* __restrict__ w_up,
    const float* __restrict__ g_up, const float* __restrict__ b_up,
    const float* __restrict__ m_up, const float* __restrict__ v_up,
    float* __restrict__ f1t,
    const float* __restrict__ p1, const float* __restrict__ p2,
    int* __restrict__ nn_idx, float* __restrict__ nn_w,
    float* __restrict__ out1)
{
    __shared__ float4 raw4[2130];   // 34080 B: max(GEMM 20480/epilogue 34048, NN 32896)
    int bid = blockIdx.x;
    if (bid < 128) {
        int nb = bid & 15, cb = (bid >> 4) & 1, b = bid >> 5;
        gemm_body<CIN_, 0>((char*)raw4, b, cb * 128, nb * 128,
                           x1, w_up, g_up, b_up, m_up, v_up, f1t,
                           nullptr, nullptr, nullptr, N_);
    } else {
        int v = bid - 128;
        int mb = v & 255, b = v >> 8;
        three_nn_body((float4(*)[257])raw4, b, mb, p1, p2, nn_idx, nn_w, out1);
    }
}

// ---------------------------------------------------------------------------
// Dispatch 2: lateral GEMM + interpolation (MODE 1). L2 invalidate at entry
// makes normal cached loads of f1t/nn_* safe (correct data at L3).
// ---------------------------------------------------------------------------
__global__ __launch_bounds__(256) void lat_kernel(
    const float* __restrict__ x2, const float* __restrict__ w_lat,
    const float* __restrict__ g_lat, const float* __restrict__ b_lat,
    const float* __restrict__ m_lat, const float* __restrict__ v_lat,
    const float* __restrict__ f1t, const int* __restrict__ nn_idx,
    const float* __restrict__ nn_w, float* __restrict__ out0)
{
    __shared__ float4 raw4[1280];   // 20480 B
    l2_invalidate();
    gemm_body<COUT_, 1>((char*)raw4, blockIdx.z, blockIdx.y * 128, blockIdx.x * 128,
                        x2, w_lat, g_lat, b_lat, m_lat, v_lat, out0,
                        f1t, nn_idx, nn_w, M_);
}

// ---------------------------------------------------------------------------
extern "C" void kernel_launch(void* const* d_in, const int* in_sizes, int n_in,
                              void* d_out, int out_size, void* d_ws, size_t ws_size,
                              hipStream_t stream)
{
    (void)in_sizes; (void)n_in; (void)out_size; (void)ws_size;

    const float* x1    = (const float*)d_in[0];
    const float* p1    = (const float*)d_in[1];
    const float* x2    = (const float*)d_in[2];
    const float* p2    = (const float*)d_in[3];
    const float* w_up  = (const float*)d_in[4];
    const float* g_up  = (const float*)d_in[5];
    const float* b_up  = (const float*)d_in[6];
    const float* m_up  = (const float*)d_in[7];
    const float* v_up  = (const float*)d_in[8];
    const float* w_lat = (const float*)d_in[9];
    const float* g_lat = (const float*)d_in[10];
    const float* b_lat = (const float*)d_in[11];
    const float* m_lat = (const float*)d_in[12];
    const float* v_lat = (const float*)d_in[13];

    float* out0 = (float*)d_out;
    float* out1 = out0 + (size_t)B_ * COUT_ * M_;   // p2 passthrough

    // workspace layout: f1t (8 MB) | nn_idx (384 KB) | nn_w (384 KB)
    float* f1t   = (float*)d_ws;
    int*   nn_idx = (int*)((char*)d_ws + (size_t)B_ * N_ * COUT_ * 4);
    float* nn_w   = (float*)((char*)nn_idx + (size_t)B_ * M_ * 3 * 4);

    up_nn_kernel<<<dim3(128 + 1024), 256, 0, stream>>>(
        x1, w_up, g_up, b_up, m_up, v_up, f1t, p1, p2, nn_idx, nn_w, out1);

    lat_kernel<<<dim3(M_ / 128, COUT_ / 128, B_), 256, 0, stream>>>(
        x2, w_lat, g_lat, b_lat, m_lat, v_lat, f1t, nn_idx, nn_w, out0);
}

// Round 10
// 103.425 us; speedup vs baseline: 3.4965x; 1.1160x over previous
//
#include <hip/hip_runtime.h>
#include <math.h>
#include <float.h>

#define B_    4
#define N_    2048
#define M_    8192
#define CIN_  512
#define COUT_ 256

typedef __attribute__((ext_vector_type(8))) short short8v;   // 8 bf16
typedef __attribute__((ext_vector_type(4))) float f32x4;

// ---------------------------------------------------------------------------
// d_ws handoff: producers store with system scope (sc0 sc1 -> L3 coherence
// point). Consumers run after inv_kernel invalidated every XCD's L1/L2, so
// normal cached loads are safe AND L2-cacheable. (Round-4 divergence root
// cause; round-8 showed sc-loads cost ~500cy/dword; round-9 showed per-block
// inv wipes warm L2 -> hoisted into one pre-kernel here.)
// ---------------------------------------------------------------------------
__device__ __forceinline__ void ws_store_f32(float* p, float v) {
    __hip_atomic_store((unsigned int*)p, __float_as_uint(v),
                       __ATOMIC_RELAXED, __HIP_MEMORY_SCOPE_SYSTEM);
}
__device__ __forceinline__ void ws_store_u32(int* p, int v) {
    __hip_atomic_store((unsigned int*)p, (unsigned int)v,
                       __ATOMIC_RELAXED, __HIP_MEMORY_SCOPE_SYSTEM);
}

__global__ __launch_bounds__(64) void inv_kernel() {
    asm volatile("buffer_inv sc0 sc1" ::: "memory");
}

__device__ __forceinline__ unsigned short f2bf(float f) {   // RNE f32->bf16
    unsigned u = __float_as_uint(f);
    u += 0x7fffu + ((u >> 16) & 1u);
    return (unsigned short)(u >> 16);
}

// ---------------------------------------------------------------------------
// bf16-MFMA GEMM body: out[c][m] = sum_k W[c][k] * X[k][m]  (per batch)
// Block tile 128c x 128m, 4 waves (2c x 2m), wave tile 64x64 (4x4 accs),
// K-steps of 32 (mfma_f32_16x16x32_bf16), fp32->bf16 RNE during staging.
// Register prefetch across K-steps: next step's global loads issue before the
// barrier, latency hides under frag reads + MFMA of the current step.
// MODE 0 (up):  BN+ReLU -> LDS transpose -> sc-stores f1t[n][c]
// MODE 1 (lat): BN+ReLU + 3-NN interp add (cached nnrec/f1t loads) -> out0
// ---------------------------------------------------------------------------
template<int K, int MODE>
__device__ __forceinline__ void gemm_body(
    char* raw, int b, int c0, int m0,
    const float* __restrict__ X, const float* __restrict__ W,
    const float* __restrict__ gam, const float* __restrict__ bet,
    const float* __restrict__ mu, const float* __restrict__ var,
    float* __restrict__ dst,
    const float* __restrict__ f1t, const float* __restrict__ nnrec, int Mdim)
{
    char* Ab = raw;            // A: [128 c][40 bf16]  row stride 80 B
    char* Bb = raw + 10240;    // B: [128 m][40 bf16]

    const int tid = threadIdx.x;
    const int l  = tid & 63;
    const int wv = tid >> 6;
    const int wc = wv & 1, wn = wv >> 1;

    f32x4 acc[4][4];
    #pragma unroll
    for (int i = 0; i < 4; ++i)
        #pragma unroll
        for (int j = 0; j < 4; ++j)
            acc[i][j] = (f32x4){0.f, 0.f, 0.f, 0.f};

    const int ksA = tid & 7;          // k-seg for A staging (float4 along k)
    const int crA = tid >> 3;         // c 0..31 (+32r)
    const int kqB = tid >> 5;         // k-quad 0..7 for B staging
    const int mlB = tid & 31;         // m lane (+32jj)

    float4 wreg[4];
    float  xreg[4][4];
    #pragma unroll
    for (int r = 0; r < 4; ++r)
        wreg[r] = *(const float4*)(W + (size_t)(c0 + crA + 32 * r) * K + ksA * 4);
    #pragma unroll
    for (int jj = 0; jj < 4; ++jj) {
        const float* xp = X + ((size_t)b * K + kqB * 4) * Mdim + m0 + mlB + 32 * jj;
        xreg[jj][0] = xp[0];
        xreg[jj][1] = xp[(size_t)Mdim];
        xreg[jj][2] = xp[(size_t)2 * Mdim];
        xreg[jj][3] = xp[(size_t)3 * Mdim];
    }

    for (int kc = 0; kc < K; kc += 32) {
        #pragma unroll
        for (int r = 0; r < 4; ++r) {
            unsigned lo = f2bf(wreg[r].x) | ((unsigned)f2bf(wreg[r].y) << 16);
            unsigned hi = f2bf(wreg[r].z) | ((unsigned)f2bf(wreg[r].w) << 16);
            *(uint2*)(Ab + (crA + 32 * r) * 80 + ksA * 8) = make_uint2(lo, hi);
        }
        #pragma unroll
        for (int jj = 0; jj < 4; ++jj) {
            unsigned lo = f2bf(xreg[jj][0]) | ((unsigned)f2bf(xreg[jj][1]) << 16);
            unsigned hi = f2bf(xreg[jj][2]) | ((unsigned)f2bf(xreg[jj][3]) << 16);
            *(uint2*)(Bb + (mlB + 32 * jj) * 80 + kqB * 8) = make_uint2(lo, hi);
        }
        if (kc + 32 < K) {   // prefetch next K-step into regs
            #pragma unroll
            for (int r = 0; r < 4; ++r)
                wreg[r] = *(const float4*)(W + (size_t)(c0 + crA + 32 * r) * K + (kc + 32) + ksA * 4);
            #pragma unroll
            for (int jj = 0; jj < 4; ++jj) {
                const float* xp = X + ((size_t)b * K + (kc + 32) + kqB * 4) * Mdim + m0 + mlB + 32 * jj;
                xreg[jj][0] = xp[0];
                xreg[jj][1] = xp[(size_t)Mdim];
                xreg[jj][2] = xp[(size_t)2 * Mdim];
                xreg[jj][3] = xp[(size_t)3 * Mdim];
            }
        }
        __syncthreads();
        short8v a[4], bfv[4];
        #pragma unroll
        for (int ci = 0; ci < 4; ++ci)
            a[ci] = *(const short8v*)(Ab + (wc * 64 + ci * 16 + (l & 15)) * 80 + (l >> 4) * 16);
        #pragma unroll
        for (int ni = 0; ni < 4; ++ni)
            bfv[ni] = *(const short8v*)(Bb + (wn * 64 + ni * 16 + (l & 15)) * 80 + (l >> 4) * 16);
        #pragma unroll
        for (int ci = 0; ci < 4; ++ci)
            #pragma unroll
            for (int ni = 0; ni < 4; ++ni)
                acc[ci][ni] = __builtin_amdgcn_mfma_f32_16x16x32_bf16(
                    a[ci], bfv[ni], acc[ci][ni], 0, 0, 0);
        __syncthreads();
    }

    const int lc = (l >> 4) * 4;
    float scA[4][4], shA[4][4];
    #pragma unroll
    for (int ci = 0; ci < 4; ++ci)
        #pragma unroll
        for (int r = 0; r < 4; ++r) {
            int c = c0 + wc * 64 + ci * 16 + lc + r;
            float sc = gam[c] / sqrtf(var[c] + 1e-5f);
            scA[ci][r] = sc;
            shA[ci][r] = bet[c] - mu[c] * sc;
        }

    if constexpr (MODE == 0) {
        float* S = (float*)raw;   // [64][133] f32
        #pragma unroll
        for (int h = 0; h < 2; ++h) {
            if (wn == h) {
                #pragma unroll
                for (int ni = 0; ni < 4; ++ni)
                    #pragma unroll
                    for (int ci = 0; ci < 4; ++ci)
                        #pragma unroll
                        for (int r = 0; r < 4; ++r)
                            S[(ni * 16 + (l & 15)) * 133 + wc * 64 + ci * 16 + lc + r] =
                                fmaxf(acc[ci][ni][r] * scA[ci][r] + shA[ci][r], 0.f);
            }
            __syncthreads();
            #pragma unroll
            for (int i = 0; i < 32; ++i) {
                int e = tid + i * 256;
                int row = e >> 7, c = e & 127;
                ws_store_f32(dst + ((size_t)b * N_ + m0 + h * 64 + row) * COUT_ + c0 + c,
                             S[row * 133 + c]);
            }
            __syncthreads();
        }
    } else {
        #pragma unroll
        for (int ni = 0; ni < 4; ++ni) {
            int mg = m0 + wn * 64 + ni * 16 + (l & 15);
            const float* rp = nnrec + ((size_t)b * M_ + mg) * 8;
            float4 ra = *(const float4*)rp;        // {i0,i1,i2,w0}
            float2 rb = *(const float2*)(rp + 4);  // {w1,w2}
            int   i0 = __float_as_int(ra.x);
            int   i1 = __float_as_int(ra.y);
            int   i2 = __float_as_int(ra.z);
            float w0 = ra.w, w1 = rb.x, w2 = rb.y;
            const float4* g0 = (const float4*)(f1t + ((size_t)b * N_ + i0) * COUT_ + c0 + wc * 64 + lc);
            const float4* g1 = (const float4*)(f1t + ((size_t)b * N_ + i1) * COUT_ + c0 + wc * 64 + lc);
            const float4* g2 = (const float4*)(f1t + ((size_t)b * N_ + i2) * COUT_ + c0 + wc * 64 + lc);
            #pragma unroll
            for (int ci = 0; ci < 4; ++ci) {
                float4 G0 = g0[ci * 4];
                float4 G1 = g1[ci * 4];
                float4 G2 = g2[ci * 4];
                const float* f0 = (const float*)&G0;
                const float* f1 = (const float*)&G1;
                const float* f2 = (const float*)&G2;
                #pragma unroll
                for (int r = 0; r < 4; ++r) {
                    float v = fmaxf(acc[ci][ni][r] * scA[ci][r] + shA[ci][r], 0.f);
                    v = fmaf(w0, f0[r], v);
                    v = fmaf(w1, f1[r], v);
                    v = fmaf(w2, f2[r], v);
                    int c = c0 + wc * 64 + ci * 16 + lc + r;
                    dst[((size_t)b * COUT_ + c) * M_ + mg] = v;
                }
            }
        }
    }
}

__global__ __launch_bounds__(256) void up_kernel(
    const float* __restrict__ x1, const float* __restrict__ w_up,
    const float* __restrict__ g_up, const float* __restrict__ b_up,
    const float* __restrict__ m_up, const float* __restrict__ v_up,
    float* __restrict__ f1t)
{
    __shared__ float4 raw4[2130];   // 34080 B (epilogue S[64][133] needs 34048)
    gemm_body<CIN_, 0>((char*)raw4, blockIdx.z, blockIdx.y * 128, blockIdx.x * 128,
                       x1, w_up, g_up, b_up, m_up, v_up, f1t,
                       nullptr, nullptr, N_);
}

__global__ __launch_bounds__(256) void lat_kernel(
    const float* __restrict__ x2, const float* __restrict__ w_lat,
    const float* __restrict__ g_lat, const float* __restrict__ b_lat,
    const float* __restrict__ m_lat, const float* __restrict__ v_lat,
    const float* __restrict__ f1t, const float* __restrict__ nnrec,
    float* __restrict__ out0)
{
    __shared__ float4 raw4[1280];   // 20480 B
    gemm_body<COUT_, 1>((char*)raw4, blockIdx.z, blockIdx.y * 128, blockIdx.x * 128,
                        x2, w_lat, g_lat, b_lat, m_lat, v_lat, out0,
                        f1t, nnrec, M_);
}

// ---------------------------------------------------------------------------
// three_nn: 8 lanes/query over disjoint 256-candidate segments; candidate
// chunks of 8 read as b128 from padded LDS with REGISTER PING-PONG prefetch
// (load chunk j+1 while the 152-instr insert phase of chunk j runs -> hides
// the ~120cy LDS latency that capped VALUBusy at 53% in round 9).
// d^2 bits identical to validated rounds:
//   s = fma(z,z, fma(y,y, x*x)); dot likewise; d2 = max(fma(-2,dot,s2+s1),0)
// Branchless bubble-insert (ascending scan -> stability free); butterfly
// merge keeps lexicographic (d2, idx). Packed 8-float nnrec per query.
// ---------------------------------------------------------------------------
__device__ __forceinline__ void lex_insert(float e, int j,
    float& D0, float& D1, float& D2, int& I0, int& I1, int& I2)
{
    bool l0 = (e < D0) || (e == D0 && j < I0);
    bool l1 = (e < D1) || (e == D1 && j < I1);
    bool l2 = (e < D2) || (e == D2 && j < I2);
    if (l2) {
        if (l0)      { D2=D1; I2=I1; D1=D0; I1=I0; D0=e; I0=j; }
        else if (l1) { D2=D1; I2=I1; D1=e;  I1=j; }
        else         { D2=e;  I2=j; }
    }
}

__device__ __forceinline__ void bubble_insert(float e, int ie,
    float& D0, float& D1, float& D2, int& I0, int& I1, int& I2)
{
    bool l2 = e < D2;
    D2 = l2 ? e  : D2;
    I2 = l2 ? ie : I2;
    bool s1 = D2 < D1;
    float tf = D1; int ti = I1;
    D1 = s1 ? D2 : D1;  I1 = s1 ? I2 : I1;
    D2 = s1 ? tf : D2;  I2 = s1 ? ti : I2;
    bool s0 = D1 < D0;
    tf = D0; ti = I0;
    D0 = s0 ? D1 : D0;  I0 = s0 ? I1 : I0;
    D1 = s0 ? tf : D1;  I1 = s0 ? ti : I1;
}

__global__ __launch_bounds__(256) void three_nn_kernel(
    const float* __restrict__ p1, const float* __restrict__ p2,
    float* __restrict__ nnrec, float* __restrict__ out1)
{
    __shared__ float4 P[8][257];
    const int b = blockIdx.y;
    #pragma unroll
    for (int r = 0; r < 8; ++r) {
        int n = r * 256 + threadIdx.x;
        float x = p1[((size_t)(b*N_)+n)*3 + 0];
        float y = p1[((size_t)(b*N_)+n)*3 + 1];
        float z = p1[((size_t)(b*N_)+n)*3 + 2];
        float t = x * x;
        t = fmaf(y, y, t);
        t = fmaf(z, z, t);
        P[r][threadIdx.x] = make_float4(x, y, z, t);
    }
    __syncthreads();

    const int m = blockIdx.x * 32 + (threadIdx.x >> 3);
    const int s = threadIdx.x & 7;
    const size_t pbase = ((size_t)(b*M_) + m) * 3;
    const float qx = p2[pbase+0], qy = p2[pbase+1], qz = p2[pbase+2];
    float s2 = qx * qx;
    s2 = fmaf(qy, qy, s2);
    s2 = fmaf(qz, qz, s2);

    float D0 = FLT_MAX, D1 = FLT_MAX, D2 = FLT_MAX;
    int   I0 = 0x7fffffff, I1 = 0x7fffffff, I2 = 0x7fffffff;
    const int base = s * 256;
    const float4* Ps = &P[s][0];

    float4 ca[8], cb[8];
    #pragma unroll
    for (int u = 0; u < 8; ++u) ca[u] = Ps[u];

    #define PROC(CV, IB)                                                     \
        {                                                                    \
            float d[8];                                                      \
            _Pragma("unroll")                                                \
            for (int u = 0; u < 8; ++u) {                                    \
                float dot = qx * CV[u].x;                                    \
                dot = fmaf(qy, CV[u].y, dot);                                \
                dot = fmaf(qz, CV[u].z, dot);                                \
                float d2 = fmaf(-2.0f, dot, s2 + CV[u].w);                   \
                d[u] = fmaxf(d2, 0.0f);                                      \
            }                                                                \
            _Pragma("unroll")                                                \
            for (int u = 0; u < 8; ++u)                                      \
                bubble_insert(d[u], (IB) + u, D0, D1, D2, I0, I1, I2);       \
        }

    for (int j = 0; j < 32; j += 2) {
        #pragma unroll
        for (int u = 0; u < 8; ++u) cb[u] = Ps[(j + 1) * 8 + u];
        PROC(ca, base + j * 8);
        if (j + 2 < 32) {
            #pragma unroll
            for (int u = 0; u < 8; ++u) ca[u] = Ps[(j + 2) * 8 + u];
        }
        PROC(cb, base + (j + 1) * 8);
    }
    #undef PROC

    #pragma unroll
    for (int st = 1; st <= 4; st <<= 1) {
        float E0 = __shfl_xor(D0, st), E1 = __shfl_xor(D1, st), E2 = __shfl_xor(D2, st);
        int   J0 = __shfl_xor(I0, st), J1 = __shfl_xor(I1, st), J2 = __shfl_xor(I2, st);
        lex_insert(E0, J0, D0, D1, D2, I0, I1, I2);
        lex_insert(E1, J1, D0, D1, D2, I0, I1, I2);
        lex_insert(E2, J2, D0, D1, D2, I0, I1, I2);
    }
    if (s == 0) {
        float r0 = 1.0f / (D0 + 1e-8f);
        float r1 = 1.0f / (D1 + 1e-8f);
        float r2 = 1.0f / (D2 + 1e-8f);
        float sum = (r0 + r1) + r2;
        float* rp = nnrec + ((size_t)(b*M_) + m) * 8;
        ws_store_u32((int*)rp + 0, I0);
        ws_store_u32((int*)rp + 1, I1);
        ws_store_u32((int*)rp + 2, I2);
        ws_store_f32(rp + 3, r0 / sum);
        ws_store_f32(rp + 4, r1 / sum);
        ws_store_f32(rp + 5, r2 / sum);
        size_t o = ((size_t)(b*M_) + m) * 3;
        out1[o+0] = qx; out1[o+1] = qy; out1[o+2] = qz;
    }
}

// ---------------------------------------------------------------------------
extern "C" void kernel_launch(void* const* d_in, const int* in_sizes, int n_in,
                              void* d_out, int out_size, void* d_ws, size_t ws_size,
                              hipStream_t stream)
{
    (void)in_sizes; (void)n_in; (void)out_size; (void)ws_size;

    const float* x1    = (const float*)d_in[0];
    const float* p1    = (const float*)d_in[1];
    const float* x2    = (const float*)d_in[2];
    const float* p2    = (const float*)d_in[3];
    const float* w_up  = (const float*)d_in[4];
    const float* g_up  = (const float*)d_in[5];
    const float* b_up  = (const float*)d_in[6];
    const float* m_up  = (const float*)d_in[7];
    const float* v_up  = (const float*)d_in[8];
    const float* w_lat = (const float*)d_in[9];
    const float* g_lat = (const float*)d_in[10];
    const float* b_lat = (const float*)d_in[11];
    const float* m_lat = (const float*)d_in[12];
    const float* v_lat = (const float*)d_in[13];

    float* out0 = (float*)d_out;
    float* out1 = out0 + (size_t)B_ * COUT_ * M_;   // p2 passthrough

    // workspace layout: f1t (8 MB) | nnrec (1 MB, 8 floats per query)
    float* f1t   = (float*)d_ws;
    float* nnrec = (float*)((char*)d_ws + (size_t)B_ * N_ * COUT_ * 4);

    up_kernel<<<dim3(N_ / 128, COUT_ / 128, B_), 256, 0, stream>>>(
        x1, w_up, g_up, b_up, m_up, v_up, f1t);

    three_nn_kernel<<<dim3(M_ / 32, B_), 256, 0, stream>>>(
        p1, p2, nnrec, out1);

    inv_kernel<<<dim3(512), 64, 0, stream>>>();

    lat_kernel<<<dim3(M_ / 128, COUT_ / 128, B_), 256, 0, stream>>>(
        x2, w_lat, g_lat, b_lat, m_lat, v_lat, f1t, nnrec, out0);
}

// Round 11
// 100.396 us; speedup vs baseline: 3.6020x; 1.0302x over previous
//
#include <hip/hip_runtime.h>
#include <math.h>
#include <float.h>

#define B_    4
#define N_    2048
#define M_    8192
#define CIN_  512
#define COUT_ 256

typedef __attribute__((ext_vector_type(8))) short short8v;   // 8 bf16
typedef __attribute__((ext_vector_type(4))) float f32x4;

// ---------------------------------------------------------------------------
// d_ws handoff: producers store system-scope (sc0 sc1 -> L3 coherence point);
// one inv_kernel invalidates all XCD L1/L2 before consumers, so consumers use
// normal cached loads. (Round 4/8/9 lessons.)
// ---------------------------------------------------------------------------
__device__ __forceinline__ void ws_store_f32(float* p, float v) {
    __hip_atomic_store((unsigned int*)p, __float_as_uint(v),
                       __ATOMIC_RELAXED, __HIP_MEMORY_SCOPE_SYSTEM);
}
__device__ __forceinline__ void ws_store_u32(int* p, int v) {
    __hip_atomic_store((unsigned int*)p, (unsigned int)v,
                       __ATOMIC_RELAXED, __HIP_MEMORY_SCOPE_SYSTEM);
}

__global__ __launch_bounds__(64) void inv_kernel() {
    asm volatile("buffer_inv sc0 sc1" ::: "memory");
}

__device__ __forceinline__ unsigned short f2bf(float f) {   // RNE f32->bf16
    unsigned u = __float_as_uint(f);
    u += 0x7fffu + ((u >> 16) & 1u);
    return (unsigned short)(u >> 16);
}

// ---------------------------------------------------------------------------
// bf16-MFMA GEMM body v2: out[c][m] = sum_k W[c][k]*X[k][m] (per batch).
// Block tile 64c x 128m, 4 waves (2c x 2m), wave tile 32x64 (acc[2][4]),
// BK=32 (mfma_f32_16x16x32_bf16), fp32->bf16 RNE during staging, K-step
// register prefetch. Smaller tile doubles grid (1024/256 blocks) -> 16
// waves/CU so the gather/store epilogues have latency-hiding company.
// MODE 0 (up):  BN+ReLU -> LDS transpose -> sc-stores f1t[n][c]
// MODE 1 (lat): BN+ReLU + 3-NN interp add; nnrec prefetched pre-K-loop.
// ---------------------------------------------------------------------------
template<int K, int MODE>
__device__ __forceinline__ void gemm_body(
    char* raw, int b, int c0, int m0,
    const float* __restrict__ X, const float* __restrict__ W,
    const float* __restrict__ gam, const float* __restrict__ bet,
    const float* __restrict__ mu, const float* __restrict__ var,
    float* __restrict__ dst,
    const float* __restrict__ f1t, const float* __restrict__ nnrec, int Mdim)
{
    char* Ab = raw;            // A: [64 c][40 bf16]   row stride 80 B
    char* Bb = raw + 5120;     // B: [128 m][40 bf16]

    const int tid = threadIdx.x;
    const int l  = tid & 63;
    const int wv = tid >> 6;
    const int wc = wv & 1, wn = wv >> 1;

    f32x4 acc[2][4];
    #pragma unroll
    for (int i = 0; i < 2; ++i)
        #pragma unroll
        for (int j = 0; j < 4; ++j)
            acc[i][j] = (f32x4){0.f, 0.f, 0.f, 0.f};

    const int ksA = tid & 7;          // k-seg for A staging (float4 along k)
    const int crA = tid >> 3;         // c 0..31 (+32r, r<2)
    const int kqB = tid >> 5;         // k-quad 0..7 for B staging
    const int mlB = tid & 31;         // m lane (+32jj)

    // MODE 1: prefetch this wave's 4 nnrec records before the K-loop
    float4 ra[4]; float2 rb[4];
    if constexpr (MODE == 1) {
        #pragma unroll
        for (int ni = 0; ni < 4; ++ni) {
            int mg = m0 + wn * 64 + ni * 16 + (l & 15);
            const float* rp = nnrec + ((size_t)b * M_ + mg) * 8;
            ra[ni] = *(const float4*)rp;
            rb[ni] = *(const float2*)(rp + 4);
        }
    }

    float4 wreg[2];
    float  xreg[4][4];
    #pragma unroll
    for (int r = 0; r < 2; ++r)
        wreg[r] = *(const float4*)(W + (size_t)(c0 + crA + 32 * r) * K + ksA * 4);
    #pragma unroll
    for (int jj = 0; jj < 4; ++jj) {
        const float* xp = X + ((size_t)b * K + kqB * 4) * Mdim + m0 + mlB + 32 * jj;
        xreg[jj][0] = xp[0];
        xreg[jj][1] = xp[(size_t)Mdim];
        xreg[jj][2] = xp[(size_t)2 * Mdim];
        xreg[jj][3] = xp[(size_t)3 * Mdim];
    }

    for (int kc = 0; kc < K; kc += 32) {
        #pragma unroll
        for (int r = 0; r < 2; ++r) {
            unsigned lo = f2bf(wreg[r].x) | ((unsigned)f2bf(wreg[r].y) << 16);
            unsigned hi = f2bf(wreg[r].z) | ((unsigned)f2bf(wreg[r].w) << 16);
            *(uint2*)(Ab + (crA + 32 * r) * 80 + ksA * 8) = make_uint2(lo, hi);
        }
        #pragma unroll
        for (int jj = 0; jj < 4; ++jj) {
            unsigned lo = f2bf(xreg[jj][0]) | ((unsigned)f2bf(xreg[jj][1]) << 16);
            unsigned hi = f2bf(xreg[jj][2]) | ((unsigned)f2bf(xreg[jj][3]) << 16);
            *(uint2*)(Bb + (mlB + 32 * jj) * 80 + kqB * 8) = make_uint2(lo, hi);
        }
        if (kc + 32 < K) {   // prefetch next K-step into regs
            #pragma unroll
            for (int r = 0; r < 2; ++r)
                wreg[r] = *(const float4*)(W + (size_t)(c0 + crA + 32 * r) * K + (kc + 32) + ksA * 4);
            #pragma unroll
            for (int jj = 0; jj < 4; ++jj) {
                const float* xp = X + ((size_t)b * K + (kc + 32) + kqB * 4) * Mdim + m0 + mlB + 32 * jj;
                xreg[jj][0] = xp[0];
                xreg[jj][1] = xp[(size_t)Mdim];
                xreg[jj][2] = xp[(size_t)2 * Mdim];
                xreg[jj][3] = xp[(size_t)3 * Mdim];
            }
        }
        __syncthreads();
        short8v a[2], bfv[4];
        #pragma unroll
        for (int ci = 0; ci < 2; ++ci)
            a[ci] = *(const short8v*)(Ab + (wc * 32 + ci * 16 + (l & 15)) * 80 + (l >> 4) * 16);
        #pragma unroll
        for (int ni = 0; ni < 4; ++ni)
            bfv[ni] = *(const short8v*)(Bb + (wn * 64 + ni * 16 + (l & 15)) * 80 + (l >> 4) * 16);
        #pragma unroll
        for (int ci = 0; ci < 2; ++ci)
            #pragma unroll
            for (int ni = 0; ni < 4; ++ni)
                acc[ci][ni] = __builtin_amdgcn_mfma_f32_16x16x32_bf16(
                    a[ci], bfv[ni], acc[ci][ni], 0, 0, 0);
        __syncthreads();
    }

    const int lc = (l >> 4) * 4;
    float scA[2][4], shA[2][4];
    #pragma unroll
    for (int ci = 0; ci < 2; ++ci)
        #pragma unroll
        for (int r = 0; r < 4; ++r) {
            int c = c0 + wc * 32 + ci * 16 + lc + r;
            float sc = gam[c] / sqrtf(var[c] + 1e-5f);
            scA[ci][r] = sc;
            shA[ci][r] = bet[c] - mu[c] * sc;
        }

    if constexpr (MODE == 0) {
        // transpose 64 n-rows per half through LDS, sc-store f1t[n][c]
        float* S = (float*)raw;   // [64][66] f32 = 16896 B
        #pragma unroll
        for (int h = 0; h < 2; ++h) {
            if (wn == h) {
                #pragma unroll
                for (int ni = 0; ni < 4; ++ni)
                    #pragma unroll
                    for (int ci = 0; ci < 2; ++ci)
                        #pragma unroll
                        for (int r = 0; r < 4; ++r)
                            S[(ni * 16 + (l & 15)) * 66 + wc * 32 + ci * 16 + lc + r] =
                                fmaxf(acc[ci][ni][r] * scA[ci][r] + shA[ci][r], 0.f);
            }
            __syncthreads();
            #pragma unroll
            for (int i = 0; i < 16; ++i) {
                int e = tid + i * 256;
                int row = e >> 6, c = e & 63;
                ws_store_f32(dst + ((size_t)b * N_ + m0 + h * 64 + row) * COUT_ + c0 + c,
                             S[row * 66 + c]);
            }
            __syncthreads();
        }
    } else {
        #pragma unroll
        for (int ni = 0; ni < 4; ++ni) {
            int mg = m0 + wn * 64 + ni * 16 + (l & 15);
            int   i0 = __float_as_int(ra[ni].x);
            int   i1 = __float_as_int(ra[ni].y);
            int   i2 = __float_as_int(ra[ni].z);
            float w0 = ra[ni].w, w1 = rb[ni].x, w2 = rb[ni].y;
            const float4* g0 = (const float4*)(f1t + ((size_t)b * N_ + i0) * COUT_ + c0 + wc * 32 + lc);
            const float4* g1 = (const float4*)(f1t + ((size_t)b * N_ + i1) * COUT_ + c0 + wc * 32 + lc);
            const float4* g2 = (const float4*)(f1t + ((size_t)b * N_ + i2) * COUT_ + c0 + wc * 32 + lc);
            #pragma unroll
            for (int ci = 0; ci < 2; ++ci) {
                float4 G0 = g0[ci * 4];
                float4 G1 = g1[ci * 4];
                float4 G2 = g2[ci * 4];
                const float* f0 = (const float*)&G0;
                const float* f1 = (const float*)&G1;
                const float* f2 = (const float*)&G2;
                #pragma unroll
                for (int r = 0; r < 4; ++r) {
                    float v = fmaxf(acc[ci][ni][r] * scA[ci][r] + shA[ci][r], 0.f);
                    v = fmaf(w0, f0[r], v);
                    v = fmaf(w1, f1[r], v);
                    v = fmaf(w2, f2[r], v);
                    int c = c0 + wc * 32 + ci * 16 + lc + r;
                    dst[((size_t)b * COUT_ + c) * M_ + mg] = v;
                }
            }
        }
    }
}

__global__ __launch_bounds__(256) void up_kernel(
    const float* __restrict__ x1, const float* __restrict__ w_up,
    const float* __restrict__ g_up, const float* __restrict__ b_up,
    const float* __restrict__ m_up, const float* __restrict__ v_up,
    float* __restrict__ f1t)
{
    __shared__ float4 raw4[1056];   // 16896 B (max of staging 15360 / S 16896)
    gemm_body<CIN_, 0>((char*)raw4, blockIdx.z, blockIdx.y * 64, blockIdx.x * 128,
                       x1, w_up, g_up, b_up, m_up, v_up, f1t,
                       nullptr, nullptr, N_);
}

__global__ __launch_bounds__(256) void lat_kernel(
    const float* __restrict__ x2, const float* __restrict__ w_lat,
    const float* __restrict__ g_lat, const float* __restrict__ b_lat,
    const float* __restrict__ m_lat, const float* __restrict__ v_lat,
    const float* __restrict__ f1t, const float* __restrict__ nnrec,
    float* __restrict__ out0)
{
    __shared__ float4 raw4[960];    // 15360 B
    gemm_body<COUT_, 1>((char*)raw4, blockIdx.z, blockIdx.y * 64, blockIdx.x * 128,
                        x2, w_lat, g_lat, b_lat, m_lat, v_lat, out0,
                        f1t, nnrec, M_);
}

// ---------------------------------------------------------------------------
// three_nn: 8 lanes/query over disjoint 256-candidate segments. Candidate
// d^2 bits identical to validated rounds:
//   s = fma(z,z, fma(y,y, x*x)); dot likewise; d2 = max(fma(-2,dot,s2+s1),0)
// NEW: 4 independent top-3 chains per lane (candidate u -> chain u&3) break
// the serial 104-op insert dependence (round-10 stall: 51us at 73% busy vs
// 17us issue floor). Each chain sees ascending indices (strict < = stable);
// chains merge with exact lexicographic (d2, idx); then 3-stage butterfly.
// ---------------------------------------------------------------------------
__device__ __forceinline__ void lex_insert(float e, int j,
    float& D0, float& D1, float& D2, int& I0, int& I1, int& I2)
{
    bool l0 = (e < D0) || (e == D0 && j < I0);
    bool l1 = (e < D1) || (e == D1 && j < I1);
    bool l2 = (e < D2) || (e == D2 && j < I2);
    if (l2) {
        if (l0)      { D2=D1; I2=I1; D1=D0; I1=I0; D0=e; I0=j; }
        else if (l1) { D2=D1; I2=I1; D1=e;  I1=j; }
        else         { D2=e;  I2=j; }
    }
}

__device__ __forceinline__ void bubble_insert(float e, int ie,
    float& D0, float& D1, float& D2, int& I0, int& I1, int& I2)
{
    bool l2 = e < D2;
    D2 = l2 ? e  : D2;
    I2 = l2 ? ie : I2;
    bool s1 = D2 < D1;
    float tf = D1; int ti = I1;
    D1 = s1 ? D2 : D1;  I1 = s1 ? I2 : I1;
    D2 = s1 ? tf : D2;  I2 = s1 ? ti : I2;
    bool s0 = D1 < D0;
    tf = D0; ti = I0;
    D0 = s0 ? D1 : D0;  I0 = s0 ? I1 : I0;
    D1 = s0 ? tf : D1;  I1 = s0 ? ti : I1;
}

__global__ __launch_bounds__(256) void three_nn_kernel(
    const float* __restrict__ p1, const float* __restrict__ p2,
    float* __restrict__ nnrec, float* __restrict__ out1)
{
    __shared__ float4 P[8][257];
    const int b = blockIdx.y;
    #pragma unroll
    for (int r = 0; r < 8; ++r) {
        int n = r * 256 + threadIdx.x;
        float x = p1[((size_t)(b*N_)+n)*3 + 0];
        float y = p1[((size_t)(b*N_)+n)*3 + 1];
        float z = p1[((size_t)(b*N_)+n)*3 + 2];
        float t = x * x;
        t = fmaf(y, y, t);
        t = fmaf(z, z, t);
        P[r][threadIdx.x] = make_float4(x, y, z, t);
    }
    __syncthreads();

    const int m = blockIdx.x * 32 + (threadIdx.x >> 3);
    const int s = threadIdx.x & 7;
    const size_t pbase = ((size_t)(b*M_) + m) * 3;
    const float qx = p2[pbase+0], qy = p2[pbase+1], qz = p2[pbase+2];
    float s2 = qx * qx;
    s2 = fmaf(qy, qy, s2);
    s2 = fmaf(qz, qz, s2);

    // 4 independent chains (static indices only -> registers)
    float D0a, D1a, D2a, D0b, D1b, D2b, D0c, D1c, D2c, D0d, D1d, D2d;
    int   I0a, I1a, I2a, I0b, I1b, I2b, I0c, I1c, I2c, I0d, I1d, I2d;
    D0a=D1a=D2a=D0b=D1b=D2b=D0c=D1c=D2c=D0d=D1d=D2d=FLT_MAX;
    I0a=I1a=I2a=I0b=I1b=I2b=I0c=I1c=I2c=I0d=I1d=I2d=0x7fffffff;

    const int base = s * 256;
    const float4* Ps = &P[s][0];

    for (int t = 0; t < 256; t += 8) {
        float4 c[8];
        #pragma unroll
        for (int u = 0; u < 8; ++u) c[u] = Ps[t + u];
        float d[8];
        #pragma unroll
        for (int u = 0; u < 8; ++u) {
            float dot = qx * c[u].x;
            dot = fmaf(qy, c[u].y, dot);
            dot = fmaf(qz, c[u].z, dot);
            float d2 = fmaf(-2.0f, dot, s2 + c[u].w);
            d[u] = fmaxf(d2, 0.0f);
        }
        // chain u&3; two rounds of 4 parallel inserts
        bubble_insert(d[0], base + t + 0, D0a, D1a, D2a, I0a, I1a, I2a);
        bubble_insert(d[1], base + t + 1, D0b, D1b, D2b, I0b, I1b, I2b);
        bubble_insert(d[2], base + t + 2, D0c, D1c, D2c, I0c, I1c, I2c);
        bubble_insert(d[3], base + t + 3, D0d, D1d, D2d, I0d, I1d, I2d);
        bubble_insert(d[4], base + t + 4, D0a, D1a, D2a, I0a, I1a, I2a);
        bubble_insert(d[5], base + t + 5, D0b, D1b, D2b, I0b, I1b, I2b);
        bubble_insert(d[6], base + t + 6, D0c, D1c, D2c, I0c, I1c, I2c);
        bubble_insert(d[7], base + t + 7, D0d, D1d, D2d, I0d, I1d, I2d);
    }

    // exact lexicographic merge of chains b,c,d into a
    float D0 = D0a, D1 = D1a, D2 = D2a;
    int   I0 = I0a, I1 = I1a, I2 = I2a;
    lex_insert(D0b, I0b, D0, D1, D2, I0, I1, I2);
    lex_insert(D1b, I1b, D0, D1, D2, I0, I1, I2);
    lex_insert(D2b, I2b, D0, D1, D2, I0, I1, I2);
    lex_insert(D0c, I0c, D0, D1, D2, I0, I1, I2);
    lex_insert(D1c, I1c, D0, D1, D2, I0, I1, I2);
    lex_insert(D2c, I2c, D0, D1, D2, I0, I1, I2);
    lex_insert(D0d, I0d, D0, D1, D2, I0, I1, I2);
    lex_insert(D1d, I1d, D0, D1, D2, I0, I1, I2);
    lex_insert(D2d, I2d, D0, D1, D2, I0, I1, I2);

    #pragma unroll
    for (int st = 1; st <= 4; st <<= 1) {
        float E0 = __shfl_xor(D0, st), E1 = __shfl_xor(D1, st), E2 = __shfl_xor(D2, st);
        int   J0 = __shfl_xor(I0, st), J1 = __shfl_xor(I1, st), J2 = __shfl_xor(I2, st);
        lex_insert(E0, J0, D0, D1, D2, I0, I1, I2);
        lex_insert(E1, J1, D0, D1, D2, I0, I1, I2);
        lex_insert(E2, J2, D0, D1, D2, I0, I1, I2);
    }
    if (s == 0) {
        float r0 = 1.0f / (D0 + 1e-8f);
        float r1 = 1.0f / (D1 + 1e-8f);
        float r2 = 1.0f / (D2 + 1e-8f);
        float sum = (r0 + r1) + r2;
        float* rp = nnrec + ((size_t)(b*M_) + m) * 8;
        ws_store_u32((int*)rp + 0, I0);
        ws_store_u32((int*)rp + 1, I1);
        ws_store_u32((int*)rp + 2, I2);
        ws_store_f32(rp + 3, r0 / sum);
        ws_store_f32(rp + 4, r1 / sum);
        ws_store_f32(rp + 5, r2 / sum);
        size_t o = ((size_t)(b*M_) + m) * 3;
        out1[o+0] = qx; out1[o+1] = qy; out1[o+2] = qz;
    }
}

// ---------------------------------------------------------------------------
extern "C" void kernel_launch(void* const* d_in, const int* in_sizes, int n_in,
                              void* d_out, int out_size, void* d_ws, size_t ws_size,
                              hipStream_t stream)
{
    (void)in_sizes; (void)n_in; (void)out_size; (void)ws_size;

    const float* x1    = (const float*)d_in[0];
    const float* p1    = (const float*)d_in[1];
    const float* x2    = (const float*)d_in[2];
    const float* p2    = (const float*)d_in[3];
    const float* w_up  = (const float*)d_in[4];
    const float* g_up  = (const float*)d_in[5];
    const float* b_up  = (const float*)d_in[6];
    const float* m_up  = (const float*)d_in[7];
    const float* v_up  = (const float*)d_in[8];
    const float* w_lat = (const float*)d_in[9];
    const float* g_lat = (const float*)d_in[10];
    const float* b_lat = (const float*)d_in[11];
    const float* m_lat = (const float*)d_in[12];
    const float* v_lat = (const float*)d_in[13];

    float* out0 = (float*)d_out;
    float* out1 = out0 + (size_t)B_ * COUT_ * M_;   // p2 passthrough

    // workspace layout: f1t (8 MB) | nnrec (1 MB, 8 floats per query)
    float* f1t   = (float*)d_ws;
    float* nnrec = (float*)((char*)d_ws + (size_t)B_ * N_ * COUT_ * 4);

    up_kernel<<<dim3(N_ / 128, COUT_ / 64, B_), 256, 0, stream>>>(
        x1, w_up, g_up, b_up, m_up, v_up, f1t);

    three_nn_kernel<<<dim3(M_ / 32, B_), 256, 0, stream>>>(
        p1, p2, nnrec, out1);

    inv_kernel<<<dim3(512), 64, 0, stream>>>();

    lat_kernel<<<dim3(M_ / 128, COUT_ / 64, B_), 256, 0, stream>>>(
        x2, w_lat, g_lat, b_lat, m_lat, v_lat, f1t, nnrec, out0);
}